// Round 14
// baseline (432.161 us; speedup 1.0000x reference)
//
#include <hip/hip_runtime.h>
#include <hip/hip_bf16.h>
#include <hip/hip_cooperative_groups.h>

namespace cg = cooperative_groups;

#define D_MODEL 256
#define NHEADS 4
#define DHEAD 64
#define BATCH 4
#define TSEQ 2048
#define CHUNK 64
#define NCHUNK (TSEQ / CHUNK)   // 32
#define NTOK (BATCH * TSEQ)     // 8192
#define NBH (BATCH * NHEADS)    // 16
#define EPSV 1e-6f
#define LSTRF 68                // fp32 LDS row stride (verified)

typedef __bf16 bf16x8 __attribute__((ext_vector_type(8)));
typedef float f32x4 __attribute__((ext_vector_type(4)));
typedef unsigned short us8 __attribute__((ext_vector_type(8)));

__device__ __forceinline__ float elu1(float a) {
    return a > 0.0f ? a + 1.0f : __expf(a);
}

__device__ __forceinline__ unsigned short f2bf(float f) {
    __hip_bfloat16 h = __float2bfloat16(f);   // RNE
    return __builtin_bit_cast(unsigned short, h);
}

__device__ __forceinline__ float bf2f(unsigned short u) {
    return __bfloat162float(__builtin_bit_cast(__hip_bfloat16, u));
}

__device__ __forceinline__ void unpack2(unsigned int u, float& lo, float& hi) {
    lo = __builtin_bit_cast(float, u << 16);
    hi = __builtin_bit_cast(float, u & 0xFFFF0000u);
}

__device__ __forceinline__ void unpack8(uint4 u, float* f) {
    unpack2(u.x, f[0], f[1]);
    unpack2(u.y, f[2], f[3]);
    unpack2(u.z, f[4], f[5]);
    unpack2(u.w, f[6], f[7]);
}

__device__ __forceinline__ bf16x8 frag8(const float* p) {
    const float4 x = *reinterpret_cast<const float4*>(p);
    const float4 y = *reinterpret_cast<const float4*>(p + 4);
    us8 u;
    u[0] = f2bf(x.x); u[1] = f2bf(x.y); u[2] = f2bf(x.z); u[3] = f2bf(x.w);
    u[4] = f2bf(y.x); u[5] = f2bf(y.y); u[6] = f2bf(y.z); u[7] = f2bf(y.w);
    return __builtin_bit_cast(bf16x8, u);
}

__device__ __forceinline__ void gld_lds16(const void* g, void* l) {
    __builtin_amdgcn_global_load_lds(
        (const __attribute__((address_space(1))) void*)g,
        (__attribute__((address_space(3))) void*)l, 16, 0, 0);
}

// ===========================================================================
// MEGA KERNEL v2: all six R12 phases, grid-stride work loops, LDS <= 64KB.
// ===========================================================================
__global__ __launch_bounds__(256, 2) void mega_kernel(
    const float* __restrict__ x,
    const float* __restrict__ Wq, const float* __restrict__ bq,
    const float* __restrict__ Wk, const float* __restrict__ bk,
    const float* __restrict__ Wv, const float* __restrict__ bv,
    const float* __restrict__ Wo, const float* __restrict__ bo,
    unsigned short* __restrict__ xb,
    unsigned short* __restrict__ Wt, unsigned short* __restrict__ Wot,
    unsigned short* __restrict__ Qb, unsigned short* __restrict__ Kb,
    unsigned short* __restrict__ Vb,
    float* __restrict__ P, float* __restrict__ Z,
    unsigned short* __restrict__ Ob, float* __restrict__ out)
{
    __shared__ __align__(16) char pool[52736];
    cg::grid_group grid = cg::this_grid();
    const int tid = threadIdx.x;
    const int nblk = gridDim.x;
    const int wave = tid >> 6, lane = tid & 63;
    const int la = lane & 15, q = lane >> 4;

    // ================= P0: converts =================
    for (int u = blockIdx.x; u < 1024; u += nblk) {
        const int i = (u * 256 + tid) * 8;
        const float4 a = *reinterpret_cast<const float4*>(&x[i]);
        const float4 b = *reinterpret_cast<const float4*>(&x[i + 4]);
        ushort4 u0 = { f2bf(a.x), f2bf(a.y), f2bf(a.z), f2bf(a.w) };
        ushort4 u1 = { f2bf(b.x), f2bf(b.y), f2bf(b.z), f2bf(b.w) };
        *reinterpret_cast<ushort4*>(&xb[i]) = u0;
        *reinterpret_cast<ushort4*>(&xb[i + 4]) = u1;
    }
    for (int w = blockIdx.x; w < 64; w += nblk) {
        float (*Ls)[65] = reinterpret_cast<float(*)[65]>(pool);
        const int wi = w >> 4, ti = w & 15;
        const int k0 = (ti >> 2) * 64, n0 = (ti & 3) * 64;
        const float* W = wi == 0 ? Wq : wi == 1 ? Wk : wi == 2 ? Wv : Wo;
#pragma unroll
        for (int i = 0; i < 16; ++i) {
            const int idx = i * 256 + tid;
            const int r = idx >> 6, c = idx & 63;
            Ls[r][c] = W[(size_t)(k0 + r) * D_MODEL + n0 + c];
        }
        __syncthreads();
        unsigned short* outp = (wi < 3)
            ? (Wt + (size_t)(wi * 256 + n0) * D_MODEL + k0)
            : (Wot + (size_t)n0 * D_MODEL + k0);
#pragma unroll
        for (int i = 0; i < 16; ++i) {
            const int idx = i * 256 + tid;
            const int rn = idx >> 6, ck = idx & 63;
            outp[(size_t)rn * D_MODEL + ck] = f2bf(Ls[ck][rn]);
        }
        __syncthreads();
    }
    __threadfence();
    grid.sync();

    // ================= P1: qkv GEMM (64x64 tiles, 1536) =================
    {
        unsigned short* As = reinterpret_cast<unsigned short*>(pool);
        unsigned short* Bs = As + 64 * 64;
        for (int tt = blockIdx.x; tt < 1536; tt += nblk) {
            const int ntile = tt % 12, mtile = tt / 12;
            const int m0 = mtile * 64, n0 = ntile * 64;
            const unsigned short* Ab = xb + (size_t)m0 * D_MODEL;
            const unsigned short* Bb = Wt + (size_t)n0 * D_MODEL;

            f32x4 acc[4];
#pragma unroll
            for (int i = 0; i < 4; ++i) acc[i] = (f32x4){0.f, 0.f, 0.f, 0.f};

            for (int k0 = 0; k0 < D_MODEL; k0 += 64) {
#pragma unroll
                for (int i = 0; i < 2; ++i) {
                    const int bslot = i * 256 + wave * 64;
                    const int slot = bslot + lane;
                    const int m = slot >> 3, s = slot & 7;
                    const int g = s ^ (m & 7);
                    gld_lds16(Ab + (size_t)m * D_MODEL + k0 + g * 8, &As[bslot * 8]);
                    gld_lds16(Bb + (size_t)m * D_MODEL + k0 + g * 8, &Bs[bslot * 8]);
                }
                __syncthreads();

                bf16x8 af[2], bfr[4][2];
#pragma unroll
                for (int kh = 0; kh < 2; ++kh) {
                    const int g = kh * 4 + q;
                    const int m = wave * 16 + la;
                    af[kh] = *reinterpret_cast<const bf16x8*>(
                        &As[m * 64 + ((g ^ (m & 7)) << 3)]);
#pragma unroll
                    for (int ni = 0; ni < 4; ++ni) {
                        const int n = ni * 16 + la;
                        bfr[ni][kh] = *reinterpret_cast<const bf16x8*>(
                            &Bs[n * 64 + ((g ^ (n & 7)) << 3)]);
                    }
                }
#pragma unroll
                for (int ni = 0; ni < 4; ++ni) {
                    acc[ni] = __builtin_amdgcn_mfma_f32_16x16x32_bf16(
                        af[0], bfr[ni][0], acc[ni], 0, 0, 0);
                    acc[ni] = __builtin_amdgcn_mfma_f32_16x16x32_bf16(
                        af[1], bfr[ni][1], acc[ni], 0, 0, 0);
                }
                __syncthreads();
            }
#pragma unroll
            for (int ni = 0; ni < 4; ++ni) {
                const int row = m0 + wave * 16 + q * 4;
                const int col = n0 + ni * 16 + la;
                const int which = col >> 8;
                const int cl = col & 255;
                unsigned short* Out = which == 0 ? Qb : which == 1 ? Kb : Vb;
                const float* bias = which == 0 ? bq : which == 1 ? bk : bv;
                const int act = (which < 2);
                const float bv2 = bias[cl];
#pragma unroll
                for (int r = 0; r < 4; ++r) {
                    float v = acc[ni][r] + bv2;
                    if (act) v = elu1(v);
                    Out[(size_t)(row + r) * D_MODEL + cl] = f2bf(v);
                }
            }
        }
    }
    __threadfence();
    grid.sync();

    // ================= P2: chunksum (512 tiles) =================
    {
        float* Ktf = reinterpret_cast<float*>(pool);
        float* Vtf = Ktf + DHEAD * LSTRF;
        for (int t2 = blockIdx.x; t2 < 512; t2 += nblk) {
            const int c  = t2 % NCHUNK;
            const int bh = t2 / NCHUNK;
            const int b = bh / NHEADS, h = bh % NHEADS;
            const size_t gbase = ((size_t)(b * TSEQ + c * CHUNK)) * D_MODEL + h * DHEAD;

#pragma unroll
            for (int i = 0; i < 2; ++i) {
                const int idx = i * 256 + tid;
                const int t = idx >> 3, e0 = (idx & 7) * 8;
                float kf[8], vf[8];
                unpack8(*reinterpret_cast<const uint4*>(&Kb[gbase + (size_t)t * D_MODEL + e0]), kf);
                unpack8(*reinterpret_cast<const uint4*>(&Vb[gbase + (size_t)t * D_MODEL + e0]), vf);
#pragma unroll
                for (int j = 0; j < 8; ++j) {
                    Ktf[(e0 + j) * LSTRF + t] = kf[j];
                    Vtf[(e0 + j) * LSTRF + t] = vf[j];
                }
            }
            __syncthreads();

            const int wm = (wave >> 1) * 32, wn = (wave & 1) * 32;
            f32x4 acc[2][2];
#pragma unroll
            for (int i = 0; i < 2; ++i)
#pragma unroll
                for (int j = 0; j < 2; ++j) acc[i][j] = (f32x4){0.f, 0.f, 0.f, 0.f};
#pragma unroll
            for (int ks = 0; ks < 2; ++ks) {
                const int ko = ks * 32 + q * 8;
                const bf16x8 a0  = frag8(&Vtf[(wm + la) * LSTRF + ko]);
                const bf16x8 a1  = frag8(&Vtf[(wm + 16 + la) * LSTRF + ko]);
                const bf16x8 bb0 = frag8(&Ktf[(wn + la) * LSTRF + ko]);
                const bf16x8 bb1 = frag8(&Ktf[(wn + 16 + la) * LSTRF + ko]);
                acc[0][0] = __builtin_amdgcn_mfma_f32_16x16x32_bf16(a0, bb0, acc[0][0], 0, 0, 0);
                acc[0][1] = __builtin_amdgcn_mfma_f32_16x16x32_bf16(a0, bb1, acc[0][1], 0, 0, 0);
                acc[1][0] = __builtin_amdgcn_mfma_f32_16x16x32_bf16(a1, bb0, acc[1][0], 0, 0, 0);
                acc[1][1] = __builtin_amdgcn_mfma_f32_16x16x32_bf16(a1, bb1, acc[1][1], 0, 0, 0);
            }

            float* Pb = P + (size_t)t2 * (DHEAD * DHEAD);
#pragma unroll
            for (int mi = 0; mi < 2; ++mi)
#pragma unroll
                for (int ni = 0; ni < 2; ++ni) {
                    const int row = wm + mi * 16 + q * 4;
                    const int col = wn + ni * 16 + la;
#pragma unroll
                    for (int r = 0; r < 4; ++r)
                        Pb[(row + r) * DHEAD + col] = acc[mi][ni][r];
                }

            if (tid < DHEAD) {
                float z = 0.f;
                for (int t = 0; t < CHUNK; ++t) z += Ktf[tid * LSTRF + t];
                Z[(size_t)t2 * DHEAD + tid] = z;
            }
            __syncthreads();
        }
    }
    __threadfence();
    grid.sync();

    // ================= P3: prefix (260 items) =================
    for (int p3 = blockIdx.x; p3 < NBH * 16 + 4; p3 += nblk) {
        if (p3 < NBH * 16) {
            const int bh = p3 >> 4;
            const int e = ((p3 & 15) << 8) + tid;
            const size_t base = (size_t)bh * NCHUNK * (DHEAD * DHEAD) + e;
            float v[NCHUNK];
#pragma unroll
            for (int c = 0; c < NCHUNK; ++c) v[c] = P[base + (size_t)c * (DHEAD * DHEAD)];
            float s = 0.f;
#pragma unroll
            for (int c = 0; c < NCHUNK; ++c) {
                const float t = v[c];
                P[base + (size_t)c * (DHEAD * DHEAD)] = s;
                s += t;
            }
        } else {
            const int j = ((p3 - NBH * 16) << 8) + tid;
            if (j < NBH * DHEAD) {
                const int bh = j >> 6, d = j & 63;
                float v[NCHUNK];
#pragma unroll
                for (int c = 0; c < NCHUNK; ++c) v[c] = Z[(bh * NCHUNK + c) * DHEAD + d];
                float s = 0.f;
#pragma unroll
                for (int c = 0; c < NCHUNK; ++c) {
                    const float t = v[c];
                    Z[(bh * NCHUNK + c) * DHEAD + d] = s;
                    s += t;
                }
            }
        }
    }
    __threadfence();
    grid.sync();

    // ================= P4: chunkout (512 tiles; Ks/At aliased) =============
    {
        float* Qs   = reinterpret_cast<float*>(pool);   // [t][d]
        float* KsAt = Qs + CHUNK * LSTRF;               // Ks then At
        float* Vtf  = KsAt + CHUNK * LSTRF;             // [m][s]
        float* zsh  = Vtf + DHEAD * LSTRF;              // [64]
        float* dnm  = zsh + DHEAD;                      // [64]

        for (int t4 = blockIdx.x; t4 < 512; t4 += nblk) {
            const int c  = t4 % NCHUNK;
            const int bh = t4 / NCHUNK;
            const int b = bh / NHEADS, h = bh % NHEADS;
            const size_t gbase = ((size_t)(b * TSEQ + c * CHUNK)) * D_MODEL + h * DHEAD;
            const float* Pp = P + (size_t)t4 * (DHEAD * DHEAD);

#pragma unroll
            for (int i = 0; i < 2; ++i) {
                const int idx = i * 256 + tid;
                const int t = idx >> 3, e0 = (idx & 7) * 8;
                float qf[8], kf[8], vf[8];
                unpack8(*reinterpret_cast<const uint4*>(&Qb[gbase + (size_t)t * D_MODEL + e0]), qf);
                unpack8(*reinterpret_cast<const uint4*>(&Kb[gbase + (size_t)t * D_MODEL + e0]), kf);
                unpack8(*reinterpret_cast<const uint4*>(&Vb[gbase + (size_t)t * D_MODEL + e0]), vf);
                *reinterpret_cast<float4*>(&Qs[t * LSTRF + e0])       = (float4){qf[0], qf[1], qf[2], qf[3]};
                *reinterpret_cast<float4*>(&Qs[t * LSTRF + e0 + 4])   = (float4){qf[4], qf[5], qf[6], qf[7]};
                *reinterpret_cast<float4*>(&KsAt[t * LSTRF + e0])     = (float4){kf[0], kf[1], kf[2], kf[3]};
                *reinterpret_cast<float4*>(&KsAt[t * LSTRF + e0 + 4]) = (float4){kf[4], kf[5], kf[6], kf[7]};
#pragma unroll
                for (int j = 0; j < 8; ++j)
                    Vtf[(e0 + j) * LSTRF + t] = vf[j];
            }
            if (tid < DHEAD)
                zsh[tid] = Z[((size_t)bh * NCHUNK + c) * DHEAD + tid];
            __syncthreads();

            const int wt = (wave >> 1) * 32, wn = (wave & 1) * 32;

            f32x4 acc[2][2];
#pragma unroll
            for (int i = 0; i < 2; ++i)
#pragma unroll
                for (int j = 0; j < 2; ++j) acc[i][j] = (f32x4){0.f, 0.f, 0.f, 0.f};
#pragma unroll
            for (int ks = 0; ks < 2; ++ks) {
                const int ko = ks * 32 + q * 8;
                const bf16x8 a0  = frag8(&Qs[(wt + la) * LSTRF + ko]);
                const bf16x8 a1  = frag8(&Qs[(wt + 16 + la) * LSTRF + ko]);
                const bf16x8 bb0 = frag8(&KsAt[(wn + la) * LSTRF + ko]);
                const bf16x8 bb1 = frag8(&KsAt[(wn + 16 + la) * LSTRF + ko]);
                acc[0][0] = __builtin_amdgcn_mfma_f32_16x16x32_bf16(a0, bb0, acc[0][0], 0, 0, 0);
                acc[0][1] = __builtin_amdgcn_mfma_f32_16x16x32_bf16(a0, bb1, acc[0][1], 0, 0, 0);
                acc[1][0] = __builtin_amdgcn_mfma_f32_16x16x32_bf16(a1, bb0, acc[1][0], 0, 0, 0);
                acc[1][1] = __builtin_amdgcn_mfma_f32_16x16x32_bf16(a1, bb1, acc[1][1], 0, 0, 0);
            }
            __syncthreads();   // all Ks reads complete before overwrite (R1 pattern)
#pragma unroll
            for (int mi = 0; mi < 2; ++mi)
#pragma unroll
                for (int ni = 0; ni < 2; ++ni) {
                    const int t0 = wt + mi * 16 + q * 4;
                    const int s  = wn + ni * 16 + la;
#pragma unroll
                    for (int r = 0; r < 4; ++r)
                        KsAt[(t0 + r) * LSTRF + s] = (s <= t0 + r) ? acc[mi][ni][r] : 0.f;
                }
            __syncthreads();

            if (tid < CHUNK) {
                float dv = 0.f;
                for (int s = 0; s < CHUNK; ++s) dv += KsAt[tid * LSTRF + s];
                for (int d = 0; d < DHEAD; ++d) dv = fmaf(Qs[tid * LSTRF + d], zsh[d], dv);
                dnm[tid] = dv + EPSV;
            }
            __syncthreads();

            f32x4 o[2][2];
#pragma unroll
            for (int i = 0; i < 2; ++i)
#pragma unroll
                for (int j = 0; j < 2; ++j) o[i][j] = (f32x4){0.f, 0.f, 0.f, 0.f};
#pragma unroll
            for (int ks = 0; ks < 2; ++ks) {
                const int ko = ks * 32 + q * 8;
                const bf16x8 a0  = frag8(&Qs[(wt + la) * LSTRF + ko]);
                const bf16x8 a1  = frag8(&Qs[(wt + 16 + la) * LSTRF + ko]);
                const bf16x8 bb0 = frag8(&Pp[(wn + la) * DHEAD + ko]);
                const bf16x8 bb1 = frag8(&Pp[(wn + 16 + la) * DHEAD + ko]);
                o[0][0] = __builtin_amdgcn_mfma_f32_16x16x32_bf16(a0, bb0, o[0][0], 0, 0, 0);
                o[0][1] = __builtin_amdgcn_mfma_f32_16x16x32_bf16(a0, bb1, o[0][1], 0, 0, 0);
                o[1][0] = __builtin_amdgcn_mfma_f32_16x16x32_bf16(a1, bb0, o[1][0], 0, 0, 0);
                o[1][1] = __builtin_amdgcn_mfma_f32_16x16x32_bf16(a1, bb1, o[1][1], 0, 0, 0);
            }
#pragma unroll
            for (int ks = 0; ks < 2; ++ks) {
                const int ko = ks * 32 + q * 8;
                const bf16x8 a0  = frag8(&KsAt[(wt + la) * LSTRF + ko]);
                const bf16x8 a1  = frag8(&KsAt[(wt + 16 + la) * LSTRF + ko]);
                const bf16x8 bb0 = frag8(&Vtf[(wn + la) * LSTRF + ko]);
                const bf16x8 bb1 = frag8(&Vtf[(wn + 16 + la) * LSTRF + ko]);
                o[0][0] = __builtin_amdgcn_mfma_f32_16x16x32_bf16(a0, bb0, o[0][0], 0, 0, 0);
                o[0][1] = __builtin_amdgcn_mfma_f32_16x16x32_bf16(a0, bb1, o[0][1], 0, 0, 0);
                o[1][0] = __builtin_amdgcn_mfma_f32_16x16x32_bf16(a1, bb0, o[1][0], 0, 0, 0);
                o[1][1] = __builtin_amdgcn_mfma_f32_16x16x32_bf16(a1, bb1, o[1][1], 0, 0, 0);
            }

#pragma unroll
            for (int mi = 0; mi < 2; ++mi)
#pragma unroll
                for (int ni = 0; ni < 2; ++ni) {
                    const int t0 = wt + mi * 16 + q * 4;
                    const int m  = wn + ni * 16 + la;
#pragma unroll
                    for (int r = 0; r < 4; ++r) {
                        const float v = o[mi][ni][r] / dnm[t0 + r];
                        Ob[gbase + (size_t)(t0 + r) * D_MODEL + m] = f2bf(v);
                    }
                }
            __syncthreads();
        }
    }
    __threadfence();
    grid.sync();

    // ================= P5: ogemm (512 tiles) =================
    {
        unsigned short* As = reinterpret_cast<unsigned short*>(pool);
        unsigned short* Bs = As + 64 * 64;
        for (int tt = blockIdx.x; tt < 512; tt += nblk) {
            const int ntile = tt & 3, mtile = tt >> 2;
            const int m0 = mtile * 64, n0 = ntile * 64;
            const unsigned short* Ab = Ob  + (size_t)m0 * D_MODEL;
            const unsigned short* Bb = Wot + (size_t)n0 * D_MODEL;

            f32x4 acc[4];
#pragma unroll
            for (int i = 0; i < 4; ++i) acc[i] = (f32x4){0.f, 0.f, 0.f, 0.f};

            for (int k0 = 0; k0 < D_MODEL; k0 += 64) {
#pragma unroll
                for (int i = 0; i < 2; ++i) {
                    const int bslot = i * 256 + wave * 64;
                    const int slot = bslot + lane;
                    const int m = slot >> 3, s = slot & 7;
                    const int g = s ^ (m & 7);
                    gld_lds16(Ab + (size_t)m * D_MODEL + k0 + g * 8, &As[bslot * 8]);
                    gld_lds16(Bb + (size_t)m * D_MODEL + k0 + g * 8, &Bs[bslot * 8]);
                }
                __syncthreads();

                bf16x8 af[2], bfr[4][2];
#pragma unroll
                for (int kh = 0; kh < 2; ++kh) {
                    const int g = kh * 4 + q;
                    const int m = wave * 16 + la;
                    af[kh] = *reinterpret_cast<const bf16x8*>(
                        &As[m * 64 + ((g ^ (m & 7)) << 3)]);
#pragma unroll
                    for (int ni = 0; ni < 4; ++ni) {
                        const int n = ni * 16 + la;
                        bfr[ni][kh] = *reinterpret_cast<const bf16x8*>(
                            &Bs[n * 64 + ((g ^ (n & 7)) << 3)]);
                    }
                }
#pragma unroll
                for (int ni = 0; ni < 4; ++ni) {
                    acc[ni] = __builtin_amdgcn_mfma_f32_16x16x32_bf16(
                        af[0], bfr[ni][0], acc[ni], 0, 0, 0);
                    acc[ni] = __builtin_amdgcn_mfma_f32_16x16x32_bf16(
                        af[1], bfr[ni][1], acc[ni], 0, 0, 0);
                }
                __syncthreads();
            }
#pragma unroll
            for (int ni = 0; ni < 4; ++ni) {
                const int row = m0 + wave * 16 + q * 4;
                const int col = n0 + ni * 16 + la;
                const float bv2 = bo[col];
#pragma unroll
                for (int r = 0; r < 4; ++r)
                    out[(size_t)(row + r) * D_MODEL + col] = acc[ni][r] + bv2;
            }
        }
    }
}

// ===========================================================================
// Fallback: verified R12 kernel suite
// ===========================================================================
__global__ __launch_bounds__(256) void convert_kernel(
    const float* __restrict__ x,
    const float* __restrict__ Wq, const float* __restrict__ Wk,
    const float* __restrict__ Wv, const float* __restrict__ Wo,
    unsigned short* __restrict__ xb,
    unsigned short* __restrict__ Wt, unsigned short* __restrict__ Wot)
{
    const int tid = threadIdx.x;
    if (blockIdx.x < NTOK * D_MODEL / 8 / 256) {
        const int i = (blockIdx.x * 256 + tid) * 8;
        const float4 a = *reinterpret_cast<const float4*>(&x[i]);
        const float4 b = *reinterpret_cast<const float4*>(&x[i + 4]);
        ushort4 u0 = { f2bf(a.x), f2bf(a.y), f2bf(a.z), f2bf(a.w) };
        ushort4 u1 = { f2bf(b.x), f2bf(b.y), f2bf(b.z), f2bf(b.w) };
        *reinterpret_cast<ushort4*>(&xb[i]) = u0;
        *reinterpret_cast<ushort4*>(&xb[i + 4]) = u1;
        return;
    }
    __shared__ float Ls[64][65];
    const int bid = blockIdx.x - NTOK * D_MODEL / 8 / 256;
    const int wi = bid >> 4, ti = bid & 15;
    const int k0 = (ti >> 2) * 64, n0 = (ti & 3) * 64;
    const float* W = wi == 0 ? Wq : wi == 1 ? Wk : wi == 2 ? Wv : Wo;
#pragma unroll
    for (int i = 0; i < 16; ++i) {
        const int idx = i * 256 + tid;
        const int r = idx >> 6, c = idx & 63;
        Ls[r][c] = W[(size_t)(k0 + r) * D_MODEL + n0 + c];
    }
    __syncthreads();
    unsigned short* outp = (wi < 3) ? (Wt + (size_t)(wi * 256 + n0) * D_MODEL + k0)
                                    : (Wot + (size_t)n0 * D_MODEL + k0);
#pragma unroll
    for (int i = 0; i < 16; ++i) {
        const int idx = i * 256 + tid;
        const int rn = idx >> 6, ck = idx & 63;
        outp[(size_t)rn * D_MODEL + ck] = f2bf(Ls[ck][rn]);
    }
}

template<int MODE>
__global__ __launch_bounds__(256) void mfma_gemm_kernel(
    const unsigned short* __restrict__ A,
    const unsigned short* __restrict__ Bt,
    const float* __restrict__ b0, const float* __restrict__ b1,
    const float* __restrict__ b2,
    void* __restrict__ O0, void* __restrict__ O1, void* __restrict__ O2)
{
    __shared__ __align__(16) unsigned short As[64 * 64];
    __shared__ __align__(16) unsigned short Bs[64 * 64];
    const int tid = threadIdx.x;
    const int wave = tid >> 6, lane = tid & 63;
    const int la = lane & 15, q = lane >> 4;

    int mtile, ntile;
    if (MODE == 0) { ntile = blockIdx.x % 12; mtile = blockIdx.x / 12; }
    else           { ntile = blockIdx.x & 3;  mtile = blockIdx.x >> 2; }
    const int m0 = mtile * 64, n0 = ntile * 64;

    const unsigned short* Ab = A  + (size_t)m0 * D_MODEL;
    const unsigned short* Bb = Bt + (size_t)n0 * D_MODEL;

    f32x4 acc[4];
#pragma unroll
    for (int i = 0; i < 4; ++i) acc[i] = (f32x4){0.f, 0.f, 0.f, 0.f};

    for (int k0 = 0; k0 < D_MODEL; k0 += 64) {
#pragma unroll
        for (int i = 0; i < 2; ++i) {
            const int bslot = i * 256 + wave * 64;
            const int slot = bslot + lane;
            const int m = slot >> 3, s = slot & 7;
            const int g = s ^ (m & 7);
            gld_lds16(Ab + (size_t)m * D_MODEL + k0 + g * 8, &As[bslot * 8]);
            gld_lds16(Bb + (size_t)m * D_MODEL + k0 + g * 8, &Bs[bslot * 8]);
        }
        __syncthreads();

        bf16x8 af[2], bfr[4][2];
#pragma unroll
        for (int kh = 0; kh < 2; ++kh) {
            const int g = kh * 4 + q;
            const int m = wave * 16 + la;
            af[kh] = *reinterpret_cast<const bf16x8*>(
                &As[m * 64 + ((g ^ (m & 7)) << 3)]);
#pragma unroll
            for (int ni = 0; ni < 4; ++ni) {
                const int n = ni * 16 + la;
                bfr[ni][kh] = *reinterpret_cast<const bf16x8*>(
                    &Bs[n * 64 + ((g ^ (n & 7)) << 3)]);
            }
        }
#pragma unroll
        for (int ni = 0; ni < 4; ++ni) {
            acc[ni] = __builtin_amdgcn_mfma_f32_16x16x32_bf16(
                af[0], bfr[ni][0], acc[ni], 0, 0, 0);
            acc[ni] = __builtin_amdgcn_mfma_f32_16x16x32_bf16(
                af[1], bfr[ni][1], acc[ni], 0, 0, 0);
        }
        __syncthreads();
    }

#pragma unroll
    for (int ni = 0; ni < 4; ++ni) {
        const int row = m0 + wave * 16 + q * 4;
        const int col = n0 + ni * 16 + la;
        if (MODE == 0) {
            const int which = col >> 8;
            const int cl = col & 255;
            unsigned short* Out = (unsigned short*)
                (which == 0 ? O0 : which == 1 ? O1 : O2);
            const float* bias = which == 0 ? b0 : which == 1 ? b1 : b2;
            const int act = (which < 2);
            const float bv = bias[cl];
#pragma unroll
            for (int r = 0; r < 4; ++r) {
                float v = acc[ni][r] + bv;
                if (act) v = elu1(v);
                Out[(size_t)(row + r) * D_MODEL + cl] = f2bf(v);
            }
        } else {
            float* Out = (float*)O0;
            const float bv = b0[col];
#pragma unroll
            for (int r = 0; r < 4; ++r)
                Out[(size_t)(row + r) * D_MODEL + col] = acc[ni][r] + bv;
        }
    }
}

__global__ __launch_bounds__(256) void chunksum_kernel(
    const unsigned short* __restrict__ Kb, const unsigned short* __restrict__ Vb,
    float* __restrict__ Pt, float* __restrict__ Zc)
{
    __shared__ __align__(16) float Ktf[DHEAD * LSTRF];
    __shared__ __align__(16) float Vtf[DHEAD * LSTRF];
    const int tid = threadIdx.x;
    const int c  = blockIdx.x % NCHUNK;
    const int bh = blockIdx.x / NCHUNK;
    const int b = bh / NHEADS, h = bh % NHEADS;
    const size_t gbase = ((size_t)(b * TSEQ + c * CHUNK)) * D_MODEL + h * DHEAD;

#pragma unroll
    for (int i = 0; i < 2; ++i) {
        const int idx = i * 256 + tid;
        const int t = idx >> 3, e0 = (idx & 7) * 8;
        float kf[8], vf[8];
        unpack8(*reinterpret_cast<const uint4*>(&Kb[gbase + (size_t)t * D_MODEL + e0]), kf);
        unpack8(*reinterpret_cast<const uint4*>(&Vb[gbase + (size_t)t * D_MODEL + e0]), vf);
#pragma unroll
        for (int j = 0; j < 8; ++j) {
            Ktf[(e0 + j) * LSTRF + t] = kf[j];
            Vtf[(e0 + j) * LSTRF + t] = vf[j];
        }
    }
    __syncthreads();

    const int wave = tid >> 6, lane = tid & 63;
    const int la = lane & 15, q = lane >> 4;
    const int wm = (wave >> 1) * 32, wn = (wave & 1) * 32;

    f32x4 acc[2][2];
#pragma unroll
    for (int i = 0; i < 2; ++i)
#pragma unroll
        for (int j = 0; j < 2; ++j) acc[i][j] = (f32x4){0.f, 0.f, 0.f, 0.f};

#pragma unroll
    for (int ks = 0; ks < 2; ++ks) {
        const int ko = ks * 32 + q * 8;
        const bf16x8 a0  = frag8(&Vtf[(wm + la) * LSTRF + ko]);
        const bf16x8 a1  = frag8(&Vtf[(wm + 16 + la) * LSTRF + ko]);
        const bf16x8 bb0 = frag8(&Ktf[(wn + la) * LSTRF + ko]);
        const bf16x8 bb1 = frag8(&Ktf[(wn + 16 + la) * LSTRF + ko]);
        acc[0][0] = __builtin_amdgcn_mfma_f32_16x16x32_bf16(a0, bb0, acc[0][0], 0, 0, 0);
        acc[0][1] = __builtin_amdgcn_mfma_f32_16x16x32_bf16(a0, bb1, acc[0][1], 0, 0, 0);
        acc[1][0] = __builtin_amdgcn_mfma_f32_16x16x32_bf16(a1, bb0, acc[1][0], 0, 0, 0);
        acc[1][1] = __builtin_amdgcn_mfma_f32_16x16x32_bf16(a1, bb1, acc[1][1], 0, 0, 0);
    }

    float* Pb = Pt + (size_t)blockIdx.x * (DHEAD * DHEAD);
#pragma unroll
    for (int mi = 0; mi < 2; ++mi)
#pragma unroll
        for (int ni = 0; ni < 2; ++ni) {
            const int row = wm + mi * 16 + q * 4;
            const int col = wn + ni * 16 + la;
#pragma unroll
            for (int r = 0; r < 4; ++r)
                Pb[(row + r) * DHEAD + col] = acc[mi][ni][r];
        }

    if (tid < DHEAD) {
        float z = 0.f;
        for (int t = 0; t < CHUNK; ++t) z += Ktf[tid * LSTRF + t];
        Zc[(size_t)blockIdx.x * DHEAD + tid] = z;
    }
}

__global__ __launch_bounds__(256) void prefix_kernel(
    float* __restrict__ P, float* __restrict__ Zc)
{
    const int tid = threadIdx.x;
    if (blockIdx.x < NBH * 16) {
        const int bh = blockIdx.x >> 4;
        const int e = ((blockIdx.x & 15) << 8) + tid;
        const size_t base = (size_t)bh * NCHUNK * (DHEAD * DHEAD) + e;
        float v[NCHUNK];
#pragma unroll
        for (int c = 0; c < NCHUNK; ++c) v[c] = P[base + (size_t)c * (DHEAD * DHEAD)];
        float s = 0.f;
#pragma unroll
        for (int c = 0; c < NCHUNK; ++c) {
            const float t = v[c];
            P[base + (size_t)c * (DHEAD * DHEAD)] = s;
            s += t;
        }
    } else {
        const int j = ((int)(blockIdx.x - NBH * 16) << 8) + tid;
        if (j < NBH * DHEAD) {
            const int bh = j >> 6, d = j & 63;
            float v[NCHUNK];
#pragma unroll
            for (int c = 0; c < NCHUNK; ++c) v[c] = Zc[(bh * NCHUNK + c) * DHEAD + d];
            float s = 0.f;
#pragma unroll
            for (int c = 0; c < NCHUNK; ++c) {
                const float t = v[c];
                Zc[(bh * NCHUNK + c) * DHEAD + d] = s;
                s += t;
            }
        }
    }
}

__global__ __launch_bounds__(256) void chunkout_kernel(
    const unsigned short* __restrict__ Qb, const unsigned short* __restrict__ Kb,
    const unsigned short* __restrict__ Vb,
    const float* __restrict__ Pt, const float* __restrict__ Zx,
    unsigned short* __restrict__ Ob)
{
    __shared__ __align__(16) float Qs[CHUNK * LSTRF];
    __shared__ __align__(16) float Ks[CHUNK * LSTRF];
    __shared__ __align__(16) float Vtf[DHEAD * LSTRF];
    __shared__ __align__(16) float At[CHUNK * LSTRF];
    __shared__ float zsh[DHEAD];
    __shared__ float dnm[CHUNK];

    const int tid = threadIdx.x;
    const int c  = blockIdx.x % NCHUNK;
    const int bh = blockIdx.x / NCHUNK;
    const int b = bh / NHEADS, h = bh % NHEADS;
    const size_t gbase = ((size_t)(b * TSEQ + c * CHUNK)) * D_MODEL + h * DHEAD;
    const float* Pp = Pt + (size_t)blockIdx.x * (DHEAD * DHEAD);

#pragma unroll
    for (int i = 0; i < 2; ++i) {
        const int idx = i * 256 + tid;
        const int t = idx >> 3, e0 = (idx & 7) * 8;
        float qf[8], kf[8], vf[8];
        unpack8(*reinterpret_cast<const uint4*>(&Qb[gbase + (size_t)t * D_MODEL + e0]), qf);
        unpack8(*reinterpret_cast<const uint4*>(&Kb[gbase + (size_t)t * D_MODEL + e0]), kf);
        unpack8(*reinterpret_cast<const uint4*>(&Vb[gbase + (size_t)t * D_MODEL + e0]), vf);
        *reinterpret_cast<float4*>(&Qs[t * LSTRF + e0])     = (float4){qf[0], qf[1], qf[2], qf[3]};
        *reinterpret_cast<float4*>(&Qs[t * LSTRF + e0 + 4]) = (float4){qf[4], qf[5], qf[6], qf[7]};
        *reinterpret_cast<float4*>(&Ks[t * LSTRF + e0])     = (float4){kf[0], kf[1], kf[2], kf[3]};
        *reinterpret_cast<float4*>(&Ks[t * LSTRF + e0 + 4]) = (float4){kf[4], kf[5], kf[6], kf[7]};
#pragma unroll
        for (int j = 0; j < 8; ++j)
            Vtf[(e0 + j) * LSTRF + t] = vf[j];
    }
    if (tid < DHEAD)
        zsh[tid] = Zx[((size_t)bh * NCHUNK + c) * DHEAD + tid];
    __syncthreads();

    const int wave = tid >> 6, lane = tid & 63;
    const int la = lane & 15, q = lane >> 4;
    const int wt = (wave >> 1) * 32, wn = (wave & 1) * 32;

    f32x4 acc[2][2];
#pragma unroll
    for (int i = 0; i < 2; ++i)
#pragma unroll
        for (int j = 0; j < 2; ++j) acc[i][j] = (f32x4){0.f, 0.f, 0.f, 0.f};
#pragma unroll
    for (int ks = 0; ks < 2; ++ks) {
        const int ko = ks * 32 + q * 8;
        const bf16x8 a0  = frag8(&Qs[(wt + la) * LSTRF + ko]);
        const bf16x8 a1  = frag8(&Qs[(wt + 16 + la) * LSTRF + ko]);
        const bf16x8 bb0 = frag8(&Ks[(wn + la) * LSTRF + ko]);
        const bf16x8 bb1 = frag8(&Ks[(wn + 16 + la) * LSTRF + ko]);
        acc[0][0] = __builtin_amdgcn_mfma_f32_16x16x32_bf16(a0, bb0, acc[0][0], 0, 0, 0);
        acc[0][1] = __builtin_amdgcn_mfma_f32_16x16x32_bf16(a0, bb1, acc[0][1], 0, 0, 0);
        acc[1][0] = __builtin_amdgcn_mfma_f32_16x16x32_bf16(a1, bb0, acc[1][0], 0, 0, 0);
        acc[1][1] = __builtin_amdgcn_mfma_f32_16x16x32_bf16(a1, bb1, acc[1][1], 0, 0, 0);
    }
#pragma unroll
    for (int mi = 0; mi < 2; ++mi)
#pragma unroll
        for (int ni = 0; ni < 2; ++ni) {
            const int t0 = wt + mi * 16 + q * 4;
            const int s  = wn + ni * 16 + la;
#pragma unroll
            for (int r = 0; r < 4; ++r)
                At[(t0 + r) * LSTRF + s] = (s <= t0 + r) ? acc[mi][ni][r] : 0.f;
        }
    __syncthreads();

    if (tid < CHUNK) {
        float dv = 0.f;
        for (int s = 0; s < CHUNK; ++s) dv += At[tid * LSTRF + s];
        for (int d = 0; d < DHEAD; ++d) dv = fmaf(Qs[tid * LSTRF + d], zsh[d], dv);
        dnm[tid] = dv + EPSV;
    }
    __syncthreads();

    f32x4 o[2][2];
#pragma unroll
    for (int i = 0; i < 2; ++i)
#pragma unroll
        for (int j = 0; j < 2; ++j) o[i][j] = (f32x4){0.f, 0.f, 0.f, 0.f};
#pragma unroll
    for (int ks = 0; ks < 2; ++ks) {
        const int ko = ks * 32 + q * 8;
        const bf16x8 a0  = frag8(&Qs[(wt + la) * LSTRF + ko]);
        const bf16x8 a1  = frag8(&Qs[(wt + 16 + la) * LSTRF + ko]);
        const bf16x8 bb0 = frag8(&Pp[(wn + la) * DHEAD + ko]);
        const bf16x8 bb1 = frag8(&Pp[(wn + 16 + la) * DHEAD + ko]);
        o[0][0] = __builtin_amdgcn_mfma_f32_16x16x32_bf16(a0, bb0, o[0][0], 0, 0, 0);
        o[0][1] = __builtin_amdgcn_mfma_f32_16x16x32_bf16(a0, bb1, o[0][1], 0, 0, 0);
        o[1][0] = __builtin_amdgcn_mfma_f32_16x16x32_bf16(a1, bb0, o[1][0], 0, 0, 0);
        o[1][1] = __builtin_amdgcn_mfma_f32_16x16x32_bf16(a1, bb1, o[1][1], 0, 0, 0);
    }
#pragma unroll
    for (int ks = 0; ks < 2; ++ks) {
        const int ko = ks * 32 + q * 8;
        const bf16x8 a0  = frag8(&At[(wt + la) * LSTRF + ko]);
        const bf16x8 a1  = frag8(&At[(wt + 16 + la) * LSTRF + ko]);
        const bf16x8 bb0 = frag8(&Vtf[(wn + la) * LSTRF + ko]);
        const bf16x8 bb1 = frag8(&Vtf[(wn + 16 + la) * LSTRF + ko]);
        o[0][0] = __builtin_amdgcn_mfma_f32_16x16x32_bf16(a0, bb0, o[0][0], 0, 0, 0);
        o[0][1] = __builtin_amdgcn_mfma_f32_16x16x32_bf16(a0, bb1, o[0][1], 0, 0, 0);
        o[1][0] = __builtin_amdgcn_mfma_f32_16x16x32_bf16(a1, bb0, o[1][0], 0, 0, 0);
        o[1][1] = __builtin_amdgcn_mfma_f32_16x16x32_bf16(a1, bb1, o[1][1], 0, 0, 0);
    }

#pragma unroll
    for (int mi = 0; mi < 2; ++mi)
#pragma unroll
        for (int ni = 0; ni < 2; ++ni) {
            const int t0 = wt + mi * 16 + q * 4;
            const int m  = wn + ni * 16 + la;
#pragma unroll
            for (int r = 0; r < 4; ++r) {
                const float v = o[mi][ni][r] / dnm[t0 + r];
                Ob[gbase + (size_t)(t0 + r) * D_MODEL + m] = f2bf(v);
            }
        }
}

extern "C" void kernel_launch(void* const* d_in, const int* in_sizes, int n_in,
                              void* d_out, int out_size, void* d_ws, size_t ws_size,
                              hipStream_t stream)
{
    const float* x  = (const float*)d_in[0];
    const float* Wq = (const float*)d_in[1];
    const float* bq = (const float*)d_in[2];
    const float* Wk = (const float*)d_in[3];
    const float* bk = (const float*)d_in[4];
    const float* Wv = (const float*)d_in[5];
    const float* bv = (const float*)d_in[6];
    const float* Wo = (const float*)d_in[7];
    const float* bo = (const float*)d_in[8];
    float* out = (float*)d_out;

    const size_t NE = (size_t)NTOK * D_MODEL;
    unsigned short* xb  = (unsigned short*)d_ws;
    unsigned short* Wt  = xb + NE;
    unsigned short* Wot = Wt + 768 * 256;
    unsigned short* Qb  = Wot + 256 * 256;
    unsigned short* Kb  = Qb + NE;
    unsigned short* Vb  = Kb + NE;
    unsigned short* Ob  = Vb + NE;
    float* P = (float*)(Ob + NE);
    float* Z = P + (size_t)NBH * NCHUNK * DHEAD * DHEAD;

    // try cooperative mega-kernel; fall back to verified R12 path on error
    bool coop_ok = false;
    int occ = 0;
    hipError_t e = hipOccupancyMaxActiveBlocksPerMultiprocessor(
        &occ, mega_kernel, 256, 0);
    if (e == hipSuccess && occ > 0) {
        int grid = occ * 256;            // 256 CUs on MI355X
        if (grid > 1536) grid = 1536;
        void* args[] = {
            (void*)&x, (void*)&Wq, (void*)&bq, (void*)&Wk, (void*)&bk,
            (void*)&Wv, (void*)&bv, (void*)&Wo, (void*)&bo,
            (void*)&xb, (void*)&Wt, (void*)&Wot,
            (void*)&Qb, (void*)&Kb, (void*)&Vb,
            (void*)&P, (void*)&Z, (void*)&Ob, (void*)&out
        };
        e = hipLaunchCooperativeKernel((const void*)mega_kernel,
                                       dim3(grid), dim3(256), args, 0, stream);
        coop_ok = (e == hipSuccess);
    }

    if (!coop_ok) {
        convert_kernel<<<NTOK * D_MODEL / 8 / 256 + 64, 256, 0, stream>>>(
            x, Wq, Wk, Wv, Wo, xb, Wt, Wot);
        mfma_gemm_kernel<0><<<(NTOK / 64) * 12, 256, 0, stream>>>(
            xb, Wt, bq, bk, bv, Qb, Kb, Vb);
        chunksum_kernel<<<NBH * NCHUNK, 256, 0, stream>>>(Kb, Vb, P, Z);
        prefix_kernel<<<NBH * 16 + 4, 256, 0, stream>>>(P, Z);
        chunkout_kernel<<<NBH * NCHUNK, 256, 0, stream>>>(Qb, Kb, Vb, P, Z, Ob);
        mfma_gemm_kernel<1><<<(NTOK / 64) * 4, 256, 0, stream>>>(
            Ob, Wot, bo, nullptr, nullptr, out, nullptr, nullptr);
    }
}

// Round 15
// 114.097 us; speedup vs baseline: 3.7877x; 3.7877x over previous
//
#include <hip/hip_runtime.h>
#include <hip/hip_bf16.h>

#define D_MODEL 256
#define NHEADS 4
#define DHEAD 64
#define BATCH 4
#define TSEQ 2048
#define CHUNK 64
#define NCHUNK (TSEQ / CHUNK)   // 32
#define NTOK (BATCH * TSEQ)     // 8192
#define NBH (BATCH * NHEADS)    // 16
#define EPSV 1e-6f
#define LSTRF 68                // fp32 LDS row stride (verified)

typedef __bf16 bf16x8 __attribute__((ext_vector_type(8)));
typedef float f32x4 __attribute__((ext_vector_type(4)));
typedef unsigned short us8 __attribute__((ext_vector_type(8)));

__device__ __forceinline__ float elu1(float a) {
    return a > 0.0f ? a + 1.0f : __expf(a);
}

__device__ __forceinline__ unsigned short f2bf(float f) {
    __hip_bfloat16 h = __float2bfloat16(f);   // RNE
    return __builtin_bit_cast(unsigned short, h);
}

__device__ __forceinline__ float bf2f(unsigned short u) {
    return __bfloat162float(__builtin_bit_cast(__hip_bfloat16, u));
}

// unpack a dword holding 2 bf16 (lo,hi) into 2 fp32 — 2 VALU ops
__device__ __forceinline__ void unpack2(unsigned int u, float& lo, float& hi) {
    lo = __builtin_bit_cast(float, u << 16);
    hi = __builtin_bit_cast(float, u & 0xFFFF0000u);
}

__device__ __forceinline__ void unpack8(uint4 u, float* f) {
    unpack2(u.x, f[0], f[1]);
    unpack2(u.y, f[2], f[3]);
    unpack2(u.z, f[4], f[5]);
    unpack2(u.w, f[6], f[7]);
}

// Build a bf16x8 MFMA fragment from 8 consecutive fp32 (16B-aligned).
// Verified class (R7): 2x float4 reads (LDS or global) + VALU cvt.
__device__ __forceinline__ bf16x8 frag8(const float* p) {
    const float4 x = *reinterpret_cast<const float4*>(p);
    const float4 y = *reinterpret_cast<const float4*>(p + 4);
    us8 u;
    u[0] = f2bf(x.x); u[1] = f2bf(x.y); u[2] = f2bf(x.z); u[3] = f2bf(x.w);
    u[4] = f2bf(y.x); u[5] = f2bf(y.y); u[6] = f2bf(y.z); u[7] = f2bf(y.w);
    return __builtin_bit_cast(bf16x8, u);
}

// async global->LDS, 16B per lane; lds ptr must be wave-uniform base.
__device__ __forceinline__ void gld_lds16(const void* g, void* l) {
    __builtin_amdgcn_global_load_lds(
        (const __attribute__((address_space(1))) void*)g,
        (__attribute__((address_space(3))) void*)l, 16, 0, 0);
}

// ---------------------------------------------------------------------------
// convert: W transposes only (64 blocks) — x conversion folded into qkv GEMM.
// ---------------------------------------------------------------------------
__global__ __launch_bounds__(256) void convert_kernel(
    const float* __restrict__ Wq, const float* __restrict__ Wk,
    const float* __restrict__ Wv, const float* __restrict__ Wo,
    unsigned short* __restrict__ Wt, unsigned short* __restrict__ Wot)
{
    __shared__ float Ls[64][65];
    const int tid = threadIdx.x;
    const int wi = blockIdx.x >> 4, ti = blockIdx.x & 15;
    const int k0 = (ti >> 2) * 64, n0 = (ti & 3) * 64;
    const float* W = wi == 0 ? Wq : wi == 1 ? Wk : wi == 2 ? Wv : Wo;
#pragma unroll
    for (int i = 0; i < 16; ++i) {
        const int idx = i * 256 + tid;
        const int r = idx >> 6, c = idx & 63;
        Ls[r][c] = W[(size_t)(k0 + r) * D_MODEL + n0 + c];
    }
    __syncthreads();
    unsigned short* outp = (wi < 3) ? (Wt + (size_t)(wi * 256 + n0) * D_MODEL + k0)
                                    : (Wot + (size_t)n0 * D_MODEL + k0);
#pragma unroll
    for (int i = 0; i < 16; ++i) {
        const int idx = i * 256 + tid;
        const int rn = idx >> 6, ck = idx & 63;
        outp[(size_t)rn * D_MODEL + ck] = f2bf(Ls[ck][rn]);
    }
}

// ---------------------------------------------------------------------------
// MFMA bf16 GEMM — 64x64 tile (R12-verified geometry & op classes).
// MODE 0: qkv — A operand is x in FP32, converted to bf16 during staging
//         (float4 global loads + f2bf pack + single 16B LDS store into the
//         same XOR-swizzled slot layout gld_lds16 produced). elu1 on Q,K.
// MODE 1: ogemm — A is bf16 Ob via gld_lds16 (unchanged); fp32 out.
// ---------------------------------------------------------------------------
template<int MODE>
__global__ __launch_bounds__(256) void mfma_gemm_kernel(
    const void* __restrict__ Avoid,
    const unsigned short* __restrict__ Bt,
    const float* __restrict__ b0, const float* __restrict__ b1,
    const float* __restrict__ b2,
    void* __restrict__ O0, void* __restrict__ O1, void* __restrict__ O2)
{
    __shared__ __align__(16) unsigned short As[64 * 64];
    __shared__ __align__(16) unsigned short Bs[64 * 64];
    const int tid = threadIdx.x;
    const int wave = tid >> 6, lane = tid & 63;
    const int la = lane & 15, q = lane >> 4;

    int mtile, ntile;
    if (MODE == 0) { ntile = blockIdx.x % 12; mtile = blockIdx.x / 12; }
    else           { ntile = blockIdx.x & 3;  mtile = blockIdx.x >> 2; }
    const int m0 = mtile * 64, n0 = ntile * 64;

    const float* Ax = (const float*)Avoid;                    // MODE 0
    const unsigned short* Ab = (const unsigned short*)Avoid;  // MODE 1
    const unsigned short* Bb = Bt + (size_t)n0 * D_MODEL;

    f32x4 acc[4];
#pragma unroll
    for (int i = 0; i < 4; ++i) acc[i] = (f32x4){0.f, 0.f, 0.f, 0.f};

    for (int k0 = 0; k0 < D_MODEL; k0 += 64) {
        // stage A: 64 rows x 64 k, XOR-swizzled slot layout
        if (MODE == 0) {
#pragma unroll
            for (int i = 0; i < 2; ++i) {
                const int slot = i * 256 + tid;     // 0..511
                const int m = slot >> 3, s = slot & 7;
                const int g = s ^ (m & 7);
                const float* src = Ax + (size_t)(m0 + m) * D_MODEL + k0 + g * 8;
                const float4 a = *reinterpret_cast<const float4*>(src);
                const float4 b = *reinterpret_cast<const float4*>(src + 4);
                us8 u;
                u[0] = f2bf(a.x); u[1] = f2bf(a.y); u[2] = f2bf(a.z); u[3] = f2bf(a.w);
                u[4] = f2bf(b.x); u[5] = f2bf(b.y); u[6] = f2bf(b.z); u[7] = f2bf(b.w);
                *reinterpret_cast<float4*>(&As[slot * 8]) =
                    __builtin_bit_cast(float4, u);
            }
        } else {
#pragma unroll
            for (int i = 0; i < 2; ++i) {
                const int bslot = i * 256 + wave * 64;   // wave-uniform base
                const int slot = bslot + lane;
                const int m = slot >> 3, s = slot & 7;
                const int g = s ^ (m & 7);
                gld_lds16(Ab + (size_t)(m0 + m) * D_MODEL + k0 + g * 8,
                          &As[bslot * 8]);
            }
        }
        // stage B via gld_lds16 (unchanged)
#pragma unroll
        for (int i = 0; i < 2; ++i) {
            const int bslot = i * 256 + wave * 64;
            const int slot = bslot + lane;
            const int m = slot >> 3, s = slot & 7;
            const int g = s ^ (m & 7);
            gld_lds16(Bb + (size_t)m * D_MODEL + k0 + g * 8, &Bs[bslot * 8]);
        }
        __syncthreads();

        bf16x8 af[2], bfr[4][2];
#pragma unroll
        for (int kh = 0; kh < 2; ++kh) {
            const int g = kh * 4 + q;
            const int m = wave * 16 + la;
            af[kh] = *reinterpret_cast<const bf16x8*>(
                &As[m * 64 + ((g ^ (m & 7)) << 3)]);
#pragma unroll
            for (int ni = 0; ni < 4; ++ni) {
                const int n = ni * 16 + la;
                bfr[ni][kh] = *reinterpret_cast<const bf16x8*>(
                    &Bs[n * 64 + ((g ^ (n & 7)) << 3)]);
            }
        }
#pragma unroll
        for (int ni = 0; ni < 4; ++ni) {
            acc[ni] = __builtin_amdgcn_mfma_f32_16x16x32_bf16(
                af[0], bfr[ni][0], acc[ni], 0, 0, 0);
            acc[ni] = __builtin_amdgcn_mfma_f32_16x16x32_bf16(
                af[1], bfr[ni][1], acc[ni], 0, 0, 0);
        }
        __syncthreads();
    }

    // C/D layout: col=lane&15, row=(lane>>4)*4+reg
#pragma unroll
    for (int ni = 0; ni < 4; ++ni) {
        const int row = m0 + wave * 16 + q * 4;
        const int col = n0 + ni * 16 + la;
        if (MODE == 0) {
            const int which = col >> 8;          // block-uniform
            const int cl = col & 255;
            unsigned short* Out = (unsigned short*)
                (which == 0 ? O0 : which == 1 ? O1 : O2);
            const float* bias = which == 0 ? b0 : which == 1 ? b1 : b2;
            const int act = (which < 2);
            const float bv = bias[cl];
#pragma unroll
            for (int r = 0; r < 4; ++r) {
                float v = acc[ni][r] + bv;
                if (act) v = elu1(v);
                Out[(size_t)(row + r) * D_MODEL + cl] = f2bf(v);
            }
        } else {
            float* Out = (float*)O0;
            const float bv = b0[col];
#pragma unroll
            for (int r = 0; r < 4; ++r)
                Out[(size_t)(row + r) * D_MODEL + col] = acc[ni][r] + bv;
        }
    }
}

// ---------------------------------------------------------------------------
// chunksum (R10/R11/R12-verified): Pt_c[m][d] = sum_t V[t][m] K[t][d]; Z_c[d].
// ---------------------------------------------------------------------------
__global__ __launch_bounds__(256) void chunksum_kernel(
    const unsigned short* __restrict__ Kb, const unsigned short* __restrict__ Vb,
    float* __restrict__ Pt, float* __restrict__ Zc)
{
    __shared__ __align__(16) float Ktf[DHEAD * LSTRF];   // Ktf[d][t]
    __shared__ __align__(16) float Vtf[DHEAD * LSTRF];   // Vtf[m][t]
    const int tid = threadIdx.x;
    const int c  = blockIdx.x % NCHUNK;
    const int bh = blockIdx.x / NCHUNK;
    const int b = bh / NHEADS, h = bh % NHEADS;
    const size_t gbase = ((size_t)(b * TSEQ + c * CHUNK)) * D_MODEL + h * DHEAD;

#pragma unroll
    for (int i = 0; i < 2; ++i) {
        const int idx = i * 256 + tid;           // 0..511
        const int t = idx >> 3, e0 = (idx & 7) * 8;
        float kf[8], vf[8];
        unpack8(*reinterpret_cast<const uint4*>(&Kb[gbase + (size_t)t * D_MODEL + e0]), kf);
        unpack8(*reinterpret_cast<const uint4*>(&Vb[gbase + (size_t)t * D_MODEL + e0]), vf);
#pragma unroll
        for (int j = 0; j < 8; ++j) {
            Ktf[(e0 + j) * LSTRF + t] = kf[j];
            Vtf[(e0 + j) * LSTRF + t] = vf[j];
        }
    }
    __syncthreads();

    const int wave = tid >> 6, lane = tid & 63;
    const int la = lane & 15, q = lane >> 4;
    const int wm = (wave >> 1) * 32, wn = (wave & 1) * 32;   // m rows, d cols

    f32x4 acc[2][2];
#pragma unroll
    for (int i = 0; i < 2; ++i)
#pragma unroll
        for (int j = 0; j < 2; ++j) acc[i][j] = (f32x4){0.f, 0.f, 0.f, 0.f};

#pragma unroll
    for (int ks = 0; ks < 2; ++ks) {
        const int ko = ks * 32 + q * 8;                       // k = t
        const bf16x8 a0  = frag8(&Vtf[(wm + la) * LSTRF + ko]);
        const bf16x8 a1  = frag8(&Vtf[(wm + 16 + la) * LSTRF + ko]);
        const bf16x8 bb0 = frag8(&Ktf[(wn + la) * LSTRF + ko]);
        const bf16x8 bb1 = frag8(&Ktf[(wn + 16 + la) * LSTRF + ko]);
        acc[0][0] = __builtin_amdgcn_mfma_f32_16x16x32_bf16(a0, bb0, acc[0][0], 0, 0, 0);
        acc[0][1] = __builtin_amdgcn_mfma_f32_16x16x32_bf16(a0, bb1, acc[0][1], 0, 0, 0);
        acc[1][0] = __builtin_amdgcn_mfma_f32_16x16x32_bf16(a1, bb0, acc[1][0], 0, 0, 0);
        acc[1][1] = __builtin_amdgcn_mfma_f32_16x16x32_bf16(a1, bb1, acc[1][1], 0, 0, 0);
    }

    float* Pb = Pt + (size_t)blockIdx.x * (DHEAD * DHEAD);
#pragma unroll
    for (int mi = 0; mi < 2; ++mi)
#pragma unroll
        for (int ni = 0; ni < 2; ++ni) {
            const int row = wm + mi * 16 + q * 4;   // m
            const int col = wn + ni * 16 + la;      // d
#pragma unroll
            for (int r = 0; r < 4; ++r)
                Pb[(row + r) * DHEAD + col] = acc[mi][ni][r];
        }

    if (tid < DHEAD) {
        float z = 0.f;
        for (int t = 0; t < CHUNK; ++t) z += Ktf[tid * LSTRF + t];
        Zc[(size_t)blockIdx.x * DHEAD + tid] = z;
    }
}

// ---------------------------------------------------------------------------
// prefix (R7/R11/R12-verified): exclusive scan over chunks, register-buffered.
// ---------------------------------------------------------------------------
__global__ __launch_bounds__(256) void prefix_kernel(
    float* __restrict__ P, float* __restrict__ Zc)
{
    const int tid = threadIdx.x;
    if (blockIdx.x < NBH * 16) {
        const int bh = blockIdx.x >> 4;
        const int e = ((blockIdx.x & 15) << 8) + tid;
        const size_t base = (size_t)bh * NCHUNK * (DHEAD * DHEAD) + e;
        float v[NCHUNK];
#pragma unroll
        for (int c = 0; c < NCHUNK; ++c) v[c] = P[base + (size_t)c * (DHEAD * DHEAD)];
        float s = 0.f;
#pragma unroll
        for (int c = 0; c < NCHUNK; ++c) {
            const float t = v[c];
            P[base + (size_t)c * (DHEAD * DHEAD)] = s;
            s += t;
        }
    } else {
        const int j = ((int)(blockIdx.x - NBH * 16) << 8) + tid;
        if (j < NBH * DHEAD) {
            const int bh = j >> 6, d = j & 63;
            float v[NCHUNK];
#pragma unroll
            for (int c = 0; c < NCHUNK; ++c) v[c] = Zc[(bh * NCHUNK + c) * DHEAD + d];
            float s = 0.f;
#pragma unroll
            for (int c = 0; c < NCHUNK; ++c) {
                const float t = v[c];
                Zc[(bh * NCHUNK + c) * DHEAD + d] = s;
                s += t;
            }
        }
    }
}

// ---------------------------------------------------------------------------
// chunkout (R11/R12-verified): MFMA compute + uint4 staging; Pt/Zx scanned.
// ---------------------------------------------------------------------------
__global__ __launch_bounds__(256) void chunkout_kernel(
    const unsigned short* __restrict__ Qb, const unsigned short* __restrict__ Kb,
    const unsigned short* __restrict__ Vb,
    const float* __restrict__ Pt, const float* __restrict__ Zx,
    unsigned short* __restrict__ Ob)
{
    __shared__ __align__(16) float Qs[CHUNK * LSTRF];    // Qs[t][d]
    __shared__ __align__(16) float Ks[CHUNK * LSTRF];    // Ks[s][d]
    __shared__ __align__(16) float Vtf[DHEAD * LSTRF];   // Vtf[m][s]
    __shared__ __align__(16) float At[CHUNK * LSTRF];    // At[t][s] masked QK^T
    __shared__ float zsh[DHEAD];
    __shared__ float dnm[CHUNK];

    const int tid = threadIdx.x;
    const int c  = blockIdx.x % NCHUNK;
    const int bh = blockIdx.x / NCHUNK;
    const int b = bh / NHEADS, h = bh % NHEADS;
    const size_t gbase = ((size_t)(b * TSEQ + c * CHUNK)) * D_MODEL + h * DHEAD;
    const float* Pp = Pt + (size_t)blockIdx.x * (DHEAD * DHEAD);

#pragma unroll
    for (int i = 0; i < 2; ++i) {
        const int idx = i * 256 + tid;
        const int t = idx >> 3, e0 = (idx & 7) * 8;
        float qf[8], kf[8], vf[8];
        unpack8(*reinterpret_cast<const uint4*>(&Qb[gbase + (size_t)t * D_MODEL + e0]), qf);
        unpack8(*reinterpret_cast<const uint4*>(&Kb[gbase + (size_t)t * D_MODEL + e0]), kf);
        unpack8(*reinterpret_cast<const uint4*>(&Vb[gbase + (size_t)t * D_MODEL + e0]), vf);
        *reinterpret_cast<float4*>(&Qs[t * LSTRF + e0])     = (float4){qf[0], qf[1], qf[2], qf[3]};
        *reinterpret_cast<float4*>(&Qs[t * LSTRF + e0 + 4]) = (float4){qf[4], qf[5], qf[6], qf[7]};
        *reinterpret_cast<float4*>(&Ks[t * LSTRF + e0])     = (float4){kf[0], kf[1], kf[2], kf[3]};
        *reinterpret_cast<float4*>(&Ks[t * LSTRF + e0 + 4]) = (float4){kf[4], kf[5], kf[6], kf[7]};
#pragma unroll
        for (int j = 0; j < 8; ++j)
            Vtf[(e0 + j) * LSTRF + t] = vf[j];
    }
    if (tid < DHEAD)
        zsh[tid] = Zx[((size_t)bh * NCHUNK + c) * DHEAD + tid];
    __syncthreads();

    const int wave = tid >> 6, lane = tid & 63;
    const int la = lane & 15, q = lane >> 4;
    const int wt = (wave >> 1) * 32, wn = (wave & 1) * 32;

    // phase 1: A = Q K^T
    f32x4 acc[2][2];
#pragma unroll
    for (int i = 0; i < 2; ++i)
#pragma unroll
        for (int j = 0; j < 2; ++j) acc[i][j] = (f32x4){0.f, 0.f, 0.f, 0.f};
#pragma unroll
    for (int ks = 0; ks < 2; ++ks) {
        const int ko = ks * 32 + q * 8;
        const bf16x8 a0  = frag8(&Qs[(wt + la) * LSTRF + ko]);
        const bf16x8 a1  = frag8(&Qs[(wt + 16 + la) * LSTRF + ko]);
        const bf16x8 bb0 = frag8(&Ks[(wn + la) * LSTRF + ko]);
        const bf16x8 bb1 = frag8(&Ks[(wn + 16 + la) * LSTRF + ko]);
        acc[0][0] = __builtin_amdgcn_mfma_f32_16x16x32_bf16(a0, bb0, acc[0][0], 0, 0, 0);
        acc[0][1] = __builtin_amdgcn_mfma_f32_16x16x32_bf16(a0, bb1, acc[0][1], 0, 0, 0);
        acc[1][0] = __builtin_amdgcn_mfma_f32_16x16x32_bf16(a1, bb0, acc[1][0], 0, 0, 0);
        acc[1][1] = __builtin_amdgcn_mfma_f32_16x16x32_bf16(a1, bb1, acc[1][1], 0, 0, 0);
    }
#pragma unroll
    for (int mi = 0; mi < 2; ++mi)
#pragma unroll
        for (int ni = 0; ni < 2; ++ni) {
            const int t0 = wt + mi * 16 + q * 4;
            const int s  = wn + ni * 16 + la;
#pragma unroll
            for (int r = 0; r < 4; ++r)
                At[(t0 + r) * LSTRF + s] = (s <= t0 + r) ? acc[mi][ni][r] : 0.f;
        }
    __syncthreads();

    // phase 2: denom[t] = rowsum(A) + Q . Z_prev + eps
    if (tid < CHUNK) {
        float dv = 0.f;
        for (int s = 0; s < CHUNK; ++s) dv += At[tid * LSTRF + s];
        for (int d = 0; d < DHEAD; ++d) dv = fmaf(Qs[tid * LSTRF + d], zsh[d], dv);
        dnm[tid] = dv + EPSV;
    }
    __syncthreads();

    // phase 3: O = Q @ S_prev + A @ V
    f32x4 o[2][2];
#pragma unroll
    for (int i = 0; i < 2; ++i)
#pragma unroll
        for (int j = 0; j < 2; ++j) o[i][j] = (f32x4){0.f, 0.f, 0.f, 0.f};
#pragma unroll
    for (int ks = 0; ks < 2; ++ks) {
        const int ko = ks * 32 + q * 8;                       // k = d
        const bf16x8 a0  = frag8(&Qs[(wt + la) * LSTRF + ko]);
        const bf16x8 a1  = frag8(&Qs[(wt + 16 + la) * LSTRF + ko]);
        const bf16x8 bb0 = frag8(&Pp[(wn + la) * DHEAD + ko]);        // global
        const bf16x8 bb1 = frag8(&Pp[(wn + 16 + la) * DHEAD + ko]);   // global
        o[0][0] = __builtin_amdgcn_mfma_f32_16x16x32_bf16(a0, bb0, o[0][0], 0, 0, 0);
        o[0][1] = __builtin_amdgcn_mfma_f32_16x16x32_bf16(a0, bb1, o[0][1], 0, 0, 0);
        o[1][0] = __builtin_amdgcn_mfma_f32_16x16x32_bf16(a1, bb0, o[1][0], 0, 0, 0);
        o[1][1] = __builtin_amdgcn_mfma_f32_16x16x32_bf16(a1, bb1, o[1][1], 0, 0, 0);
    }
#pragma unroll
    for (int ks = 0; ks < 2; ++ks) {
        const int ko = ks * 32 + q * 8;                       // k = s
        const bf16x8 a0  = frag8(&At[(wt + la) * LSTRF + ko]);
        const bf16x8 a1  = frag8(&At[(wt + 16 + la) * LSTRF + ko]);
        const bf16x8 bb0 = frag8(&Vtf[(wn + la) * LSTRF + ko]);
        const bf16x8 bb1 = frag8(&Vtf[(wn + 16 + la) * LSTRF + ko]);
        o[0][0] = __builtin_amdgcn_mfma_f32_16x16x32_bf16(a0, bb0, o[0][0], 0, 0, 0);
        o[0][1] = __builtin_amdgcn_mfma_f32_16x16x32_bf16(a0, bb1, o[0][1], 0, 0, 0);
        o[1][0] = __builtin_amdgcn_mfma_f32_16x16x32_bf16(a1, bb0, o[1][0], 0, 0, 0);
        o[1][1] = __builtin_amdgcn_mfma_f32_16x16x32_bf16(a1, bb1, o[1][1], 0, 0, 0);
    }

    // epilogue: divide + bf16 scalar stores (verified class)
#pragma unroll
    for (int mi = 0; mi < 2; ++mi)
#pragma unroll
        for (int ni = 0; ni < 2; ++ni) {
            const int t0 = wt + mi * 16 + q * 4;
            const int m  = wn + ni * 16 + la;
#pragma unroll
            for (int r = 0; r < 4; ++r) {
                const float v = o[mi][ni][r] / dnm[t0 + r];
                Ob[gbase + (size_t)(t0 + r) * D_MODEL + m] = f2bf(v);
            }
        }
}

extern "C" void kernel_launch(void* const* d_in, const int* in_sizes, int n_in,
                              void* d_out, int out_size, void* d_ws, size_t ws_size,
                              hipStream_t stream)
{
    const float* x  = (const float*)d_in[0];
    const float* Wq = (const float*)d_in[1];
    const float* bq = (const float*)d_in[2];
    const float* Wk = (const float*)d_in[3];
    const float* bk = (const float*)d_in[4];
    const float* Wv = (const float*)d_in[5];
    const float* bv = (const float*)d_in[6];
    const float* Wo = (const float*)d_in[7];
    const float* bo = (const float*)d_in[8];
    float* out = (float*)d_out;

    const size_t NE = (size_t)NTOK * D_MODEL;               // 2M elems
    unsigned short* Wt  = (unsigned short*)d_ws;            // 768*256 bf16
    unsigned short* Wot = Wt + 768 * 256;                   // 256*256
    unsigned short* Qb  = Wot + 256 * 256;                  // 2M
    unsigned short* Kb  = Qb + NE;                          // 2M
    unsigned short* Vb  = Kb + NE;                          // 2M
    unsigned short* Ob  = Vb + NE;                          // 2M
    float* P = (float*)(Ob + NE);                           // 16*32*4096 f32 (8MB)
    float* Z = P + (size_t)NBH * NCHUNK * DHEAD * DHEAD;    // 16*32*64 f32

    convert_kernel<<<64, 256, 0, stream>>>(Wq, Wk, Wv, Wo, Wt, Wot);
    mfma_gemm_kernel<0><<<(NTOK / 64) * 12, 256, 0, stream>>>(
        x, Wt, bq, bk, bv, Qb, Kb, Vb);
    chunksum_kernel<<<NBH * NCHUNK, 256, 0, stream>>>(Kb, Vb, P, Z);
    prefix_kernel<<<NBH * 16 + 4, 256, 0, stream>>>(P, Z);
    chunkout_kernel<<<NBH * NCHUNK, 256, 0, stream>>>(Qb, Kb, Vb, P, Z, Ob);
    mfma_gemm_kernel<1><<<(NTOK / 64) * 4, 256, 0, stream>>>(
        Ob, Wot, bo, nullptr, nullptr, out, nullptr, nullptr);
}

// Round 16
// 109.346 us; speedup vs baseline: 3.9522x; 1.0435x over previous
//
#include <hip/hip_runtime.h>
#include <hip/hip_bf16.h>

#define D_MODEL 256
#define NHEADS 4
#define DHEAD 64
#define BATCH 4
#define TSEQ 2048
#define CHUNK 64
#define NCHUNK (TSEQ / CHUNK)   // 32
#define NTOK (BATCH * TSEQ)     // 8192
#define NBH (BATCH * NHEADS)    // 16
#define EPSV 1e-6f
#define LSTRF 68                // fp32 LDS row stride (verified)
#define PQ 36                   // packed-bf16 LDS row stride in uints (144B, 16B-aligned)

typedef __bf16 bf16x8 __attribute__((ext_vector_type(8)));
typedef float f32x4 __attribute__((ext_vector_type(4)));
typedef unsigned short us8 __attribute__((ext_vector_type(8)));

__device__ __forceinline__ float elu1(float a) {
    return a > 0.0f ? a + 1.0f : __expf(a);
}

__device__ __forceinline__ unsigned short f2bf(float f) {
    __hip_bfloat16 h = __float2bfloat16(f);   // RNE
    return __builtin_bit_cast(unsigned short, h);
}

__device__ __forceinline__ float bf2f(unsigned short u) {
    return __bfloat162float(__builtin_bit_cast(__hip_bfloat16, u));
}

// unpack a dword holding 2 bf16 (lo,hi) into 2 fp32 — 2 VALU ops
__device__ __forceinline__ void unpack2(unsigned int u, float& lo, float& hi) {
    lo = __builtin_bit_cast(float, u << 16);
    hi = __builtin_bit_cast(float, u & 0xFFFF0000u);
}

__device__ __forceinline__ void unpack8(uint4 u, float* f) {
    unpack2(u.x, f[0], f[1]);
    unpack2(u.y, f[2], f[3]);
    unpack2(u.z, f[4], f[5]);
    unpack2(u.w, f[6], f[7]);
}

// Build a bf16x8 MFMA fragment from 8 consecutive fp32 (16B-aligned).
__device__ __forceinline__ bf16x8 frag8(const float* p) {
    const float4 x = *reinterpret_cast<const float4*>(p);
    const float4 y = *reinterpret_cast<const float4*>(p + 4);
    us8 u;
    u[0] = f2bf(x.x); u[1] = f2bf(x.y); u[2] = f2bf(x.z); u[3] = f2bf(x.w);
    u[4] = f2bf(y.x); u[5] = f2bf(y.y); u[6] = f2bf(y.z); u[7] = f2bf(y.w);
    return __builtin_bit_cast(bf16x8, u);
}

// async global->LDS, 16B per lane; lds ptr must be wave-uniform base.
__device__ __forceinline__ void gld_lds16(const void* g, void* l) {
    __builtin_amdgcn_global_load_lds(
        (const __attribute__((address_space(1))) void*)g,
        (__attribute__((address_space(3))) void*)l, 16, 0, 0);
}

// ---------------------------------------------------------------------------
// fused converts (R12-verified): blocks [0,1024): x->bf16; rest: W^T
// ---------------------------------------------------------------------------
__global__ __launch_bounds__(256) void convert_kernel(
    const float* __restrict__ x,
    const float* __restrict__ Wq, const float* __restrict__ Wk,
    const float* __restrict__ Wv, const float* __restrict__ Wo,
    unsigned short* __restrict__ xb,
    unsigned short* __restrict__ Wt, unsigned short* __restrict__ Wot)
{
    const int tid = threadIdx.x;
    if (blockIdx.x < NTOK * D_MODEL / 8 / 256) {
        const int i = (blockIdx.x * 256 + tid) * 8;
        const float4 a = *reinterpret_cast<const float4*>(&x[i]);
        const float4 b = *reinterpret_cast<const float4*>(&x[i + 4]);
        ushort4 u0 = { f2bf(a.x), f2bf(a.y), f2bf(a.z), f2bf(a.w) };
        ushort4 u1 = { f2bf(b.x), f2bf(b.y), f2bf(b.z), f2bf(b.w) };
        *reinterpret_cast<ushort4*>(&xb[i]) = u0;
        *reinterpret_cast<ushort4*>(&xb[i + 4]) = u1;
        return;
    }
    __shared__ float Ls[64][65];
    const int bid = blockIdx.x - NTOK * D_MODEL / 8 / 256;
    const int wi = bid >> 4;
    const int ti = bid & 15;
    const int k0 = (ti >> 2) * 64, n0 = (ti & 3) * 64;
    const float* W = wi == 0 ? Wq : wi == 1 ? Wk : wi == 2 ? Wv : Wo;
#pragma unroll
    for (int i = 0; i < 16; ++i) {
        const int idx = i * 256 + tid;
        const int r = idx >> 6, c = idx & 63;
        Ls[r][c] = W[(size_t)(k0 + r) * D_MODEL + n0 + c];
    }
    __syncthreads();
    unsigned short* outp = (wi < 3) ? (Wt + (size_t)(wi * 256 + n0) * D_MODEL + k0)
                                    : (Wot + (size_t)n0 * D_MODEL + k0);
#pragma unroll
    for (int i = 0; i < 16; ++i) {
        const int idx = i * 256 + tid;
        const int rn = idx >> 6, ck = idx & 63;
        outp[(size_t)rn * D_MODEL + ck] = f2bf(Ls[ck][rn]);
    }
}

// ---------------------------------------------------------------------------
// MFMA bf16 GEMM — 64x64 tile (R12-verified).
// MODE 0: qkv, grid = 128 mtiles * 12 ntiles; elu1 on Q,K; bf16 out.
// MODE 1: ogemm, grid = 128 mtiles * 4 ntiles; fp32 out.
// ---------------------------------------------------------------------------
template<int MODE>
__global__ __launch_bounds__(256) void mfma_gemm_kernel(
    const unsigned short* __restrict__ A,
    const unsigned short* __restrict__ Bt,
    const float* __restrict__ b0, const float* __restrict__ b1,
    const float* __restrict__ b2,
    void* __restrict__ O0, void* __restrict__ O1, void* __restrict__ O2)
{
    __shared__ __align__(16) unsigned short As[64 * 64];
    __shared__ __align__(16) unsigned short Bs[64 * 64];
    const int tid = threadIdx.x;
    const int wave = tid >> 6, lane = tid & 63;
    const int la = lane & 15, q = lane >> 4;

    int mtile, ntile;
    if (MODE == 0) { ntile = blockIdx.x % 12; mtile = blockIdx.x / 12; }
    else           { ntile = blockIdx.x & 3;  mtile = blockIdx.x >> 2; }
    const int m0 = mtile * 64, n0 = ntile * 64;

    const unsigned short* Ab = A  + (size_t)m0 * D_MODEL;
    const unsigned short* Bb = Bt + (size_t)n0 * D_MODEL;

    f32x4 acc[4];
#pragma unroll
    for (int i = 0; i < 4; ++i) acc[i] = (f32x4){0.f, 0.f, 0.f, 0.f};

    for (int k0 = 0; k0 < D_MODEL; k0 += 64) {
#pragma unroll
        for (int i = 0; i < 2; ++i) {
            const int bslot = i * 256 + wave * 64;   // wave-uniform base
            const int slot = bslot + lane;
            const int m = slot >> 3, s = slot & 7;
            const int g = s ^ (m & 7);
            gld_lds16(Ab + (size_t)m * D_MODEL + k0 + g * 8, &As[bslot * 8]);
            gld_lds16(Bb + (size_t)m * D_MODEL + k0 + g * 8, &Bs[bslot * 8]);
        }
        __syncthreads();

        bf16x8 af[2], bfr[4][2];
#pragma unroll
        for (int kh = 0; kh < 2; ++kh) {
            const int g = kh * 4 + q;
            const int m = wave * 16 + la;
            af[kh] = *reinterpret_cast<const bf16x8*>(
                &As[m * 64 + ((g ^ (m & 7)) << 3)]);
#pragma unroll
            for (int ni = 0; ni < 4; ++ni) {
                const int n = ni * 16 + la;
                bfr[ni][kh] = *reinterpret_cast<const bf16x8*>(
                    &Bs[n * 64 + ((g ^ (n & 7)) << 3)]);
            }
        }
#pragma unroll
        for (int ni = 0; ni < 4; ++ni) {
            acc[ni] = __builtin_amdgcn_mfma_f32_16x16x32_bf16(
                af[0], bfr[ni][0], acc[ni], 0, 0, 0);
            acc[ni] = __builtin_amdgcn_mfma_f32_16x16x32_bf16(
                af[1], bfr[ni][1], acc[ni], 0, 0, 0);
        }
        __syncthreads();
    }

    // C/D layout: col=lane&15, row=(lane>>4)*4+reg
#pragma unroll
    for (int ni = 0; ni < 4; ++ni) {
        const int row = m0 + wave * 16 + q * 4;
        const int col = n0 + ni * 16 + la;
        if (MODE == 0) {
            const int which = col >> 8;          // block-uniform
            const int cl = col & 255;
            unsigned short* Out = (unsigned short*)
                (which == 0 ? O0 : which == 1 ? O1 : O2);
            const float* bias = which == 0 ? b0 : which == 1 ? b1 : b2;
            const int act = (which < 2);
            const float bv = bias[cl];
#pragma unroll
            for (int r = 0; r < 4; ++r) {
                float v = acc[ni][r] + bv;
                if (act) v = elu1(v);
                Out[(size_t)(row + r) * D_MODEL + cl] = f2bf(v);
            }
        } else {
            float* Out = (float*)O0;
            const float bv = b0[col];
#pragma unroll
            for (int r = 0; r < 4; ++r)
                Out[(size_t)(row + r) * D_MODEL + col] = acc[ni][r] + bv;
        }
    }
}

// ---------------------------------------------------------------------------
// chunksum (R12-verified): Pt_c[m][d] = sum_t V[t][m] K[t][d]; Z_c[d].
// ---------------------------------------------------------------------------
__global__ __launch_bounds__(256) void chunksum_kernel(
    const unsigned short* __restrict__ Kb, const unsigned short* __restrict__ Vb,
    float* __restrict__ Pt, float* __restrict__ Zc)
{
    __shared__ __align__(16) float Ktf[DHEAD * LSTRF];   // Ktf[d][t]
    __shared__ __align__(16) float Vtf[DHEAD * LSTRF];   // Vtf[m][t]
    const int tid = threadIdx.x;
    const int c  = blockIdx.x % NCHUNK;
    const int bh = blockIdx.x / NCHUNK;
    const int b = bh / NHEADS, h = bh % NHEADS;
    const size_t gbase = ((size_t)(b * TSEQ + c * CHUNK)) * D_MODEL + h * DHEAD;

#pragma unroll
    for (int i = 0; i < 2; ++i) {
        const int idx = i * 256 + tid;           // 0..511
        const int t = idx >> 3, e0 = (idx & 7) * 8;
        float kf[8], vf[8];
        unpack8(*reinterpret_cast<const uint4*>(&Kb[gbase + (size_t)t * D_MODEL + e0]), kf);
        unpack8(*reinterpret_cast<const uint4*>(&Vb[gbase + (size_t)t * D_MODEL + e0]), vf);
#pragma unroll
        for (int j = 0; j < 8; ++j) {
            Ktf[(e0 + j) * LSTRF + t] = kf[j];
            Vtf[(e0 + j) * LSTRF + t] = vf[j];
        }
    }
    __syncthreads();

    const int wave = tid >> 6, lane = tid & 63;
    const int la = lane & 15, q = lane >> 4;
    const int wm = (wave >> 1) * 32, wn = (wave & 1) * 32;   // m rows, d cols

    f32x4 acc[2][2];
#pragma unroll
    for (int i = 0; i < 2; ++i)
#pragma unroll
        for (int j = 0; j < 2; ++j) acc[i][j] = (f32x4){0.f, 0.f, 0.f, 0.f};

#pragma unroll
    for (int ks = 0; ks < 2; ++ks) {
        const int ko = ks * 32 + q * 8;                       // k = t
        const bf16x8 a0  = frag8(&Vtf[(wm + la) * LSTRF + ko]);
        const bf16x8 a1  = frag8(&Vtf[(wm + 16 + la) * LSTRF + ko]);
        const bf16x8 bb0 = frag8(&Ktf[(wn + la) * LSTRF + ko]);
        const bf16x8 bb1 = frag8(&Ktf[(wn + 16 + la) * LSTRF + ko]);
        acc[0][0] = __builtin_amdgcn_mfma_f32_16x16x32_bf16(a0, bb0, acc[0][0], 0, 0, 0);
        acc[0][1] = __builtin_amdgcn_mfma_f32_16x16x32_bf16(a0, bb1, acc[0][1], 0, 0, 0);
        acc[1][0] = __builtin_amdgcn_mfma_f32_16x16x32_bf16(a1, bb0, acc[1][0], 0, 0, 0);
        acc[1][1] = __builtin_amdgcn_mfma_f32_16x16x32_bf16(a1, bb1, acc[1][1], 0, 0, 0);
    }

    float* Pb = Pt + (size_t)blockIdx.x * (DHEAD * DHEAD);
#pragma unroll
    for (int mi = 0; mi < 2; ++mi)
#pragma unroll
        for (int ni = 0; ni < 2; ++ni) {
            const int row = wm + mi * 16 + q * 4;   // m
            const int col = wn + ni * 16 + la;      // d
#pragma unroll
            for (int r = 0; r < 4; ++r)
                Pb[(row + r) * DHEAD + col] = acc[mi][ni][r];
        }

    if (tid < DHEAD) {
        float z = 0.f;
        for (int t = 0; t < CHUNK; ++t) z += Ktf[tid * LSTRF + t];
        Zc[(size_t)blockIdx.x * DHEAD + tid] = z;
    }
}

// ---------------------------------------------------------------------------
// prefix (R12-verified): exclusive scan over chunks, register-buffered.
// ---------------------------------------------------------------------------
__global__ __launch_bounds__(256) void prefix_kernel(
    float* __restrict__ P, float* __restrict__ Zc)
{
    const int tid = threadIdx.x;
    if (blockIdx.x < NBH * 16) {
        const int bh = blockIdx.x >> 4;
        const int e = ((blockIdx.x & 15) << 8) + tid;
        const size_t base = (size_t)bh * NCHUNK * (DHEAD * DHEAD) + e;
        float v[NCHUNK];
#pragma unroll
        for (int c = 0; c < NCHUNK; ++c) v[c] = P[base + (size_t)c * (DHEAD * DHEAD)];
        float s = 0.f;
#pragma unroll
        for (int c = 0; c < NCHUNK; ++c) {
            const float t = v[c];
            P[base + (size_t)c * (DHEAD * DHEAD)] = s;
            s += t;
        }
    } else {
        const int j = ((int)(blockIdx.x - NBH * 16) << 8) + tid;
        if (j < NBH * DHEAD) {
            const int bh = j >> 6, d = j & 63;
            float v[NCHUNK];
#pragma unroll
            for (int c = 0; c < NCHUNK; ++c) v[c] = Zc[(bh * NCHUNK + c) * DHEAD + d];
            float s = 0.f;
#pragma unroll
            for (int c = 0; c < NCHUNK; ++c) {
                const float t = v[c];
                Zc[(bh * NCHUNK + c) * DHEAD + d] = s;
                s += t;
            }
        }
    }
}

// ---------------------------------------------------------------------------
// chunkout — NEW: Q/K/V staged as PACKED bf16 uints in LDS (R10-verified
// Stp pattern: uint4 global load -> uint4/b32 LDS store -> direct uint4
// fragment reads). At stays fp32 (frag8 + denominator). LDS ~45.5 KB.
// ---------------------------------------------------------------------------
__global__ __launch_bounds__(256) void chunkout_kernel(
    const unsigned short* __restrict__ Qb, const unsigned short* __restrict__ Kb,
    const unsigned short* __restrict__ Vb,
    const float* __restrict__ Pt, const float* __restrict__ Zx,
    unsigned short* __restrict__ Ob)
{
    __shared__ __align__(16) unsigned int Qp[CHUNK * PQ];   // packed [t][d/2]
    __shared__ __align__(16) unsigned int Kp[CHUNK * PQ];   // packed [s][d/2]
    __shared__ __align__(16) unsigned int Vtp[DHEAD * PQ];  // packed [m][s/2]
    __shared__ __align__(16) float At[CHUNK * LSTRF];       // fp32 [t][s]
    __shared__ float zsh[DHEAD];
    __shared__ float dnm[CHUNK];

    const int tid = threadIdx.x;
    const int c  = blockIdx.x % NCHUNK;
    const int bh = blockIdx.x / NCHUNK;
    const int b = bh / NHEADS, h = bh % NHEADS;
    const size_t gbase = ((size_t)(b * TSEQ + c * CHUNK)) * D_MODEL + h * DHEAD;
    const float* Pp = Pt + (size_t)blockIdx.x * (DHEAD * DHEAD);

    // stage Q,K: straight packed 16B copies (no conversion)
#pragma unroll
    for (int i = 0; i < 2; ++i) {
        const int idx = i * 256 + tid;           // 0..511
        const int t = idx >> 3, e4 = (idx & 7) * 4;   // uint offset in row
        const uint4 qv = *reinterpret_cast<const uint4*>(
            &Qb[gbase + (size_t)t * D_MODEL + e4 * 2]);
        const uint4 kv = *reinterpret_cast<const uint4*>(
            &Kb[gbase + (size_t)t * D_MODEL + e4 * 2]);
        *reinterpret_cast<uint4*>(&Qp[t * PQ + e4]) = qv;
        *reinterpret_cast<uint4*>(&Kp[t * PQ + e4]) = kv;
    }
    // stage V transposed, packed along s: thread = (s-pair, 8 m's)
    {
        const int sp = tid & 31, mg = tid >> 5;   // sp: s/2, mg: m-group
        const int m0 = mg * 8;
        const uint4 v0 = *reinterpret_cast<const uint4*>(
            &Vb[gbase + (size_t)(2 * sp) * D_MODEL + m0]);
        const uint4 v1 = *reinterpret_cast<const uint4*>(
            &Vb[gbase + (size_t)(2 * sp + 1) * D_MODEL + m0]);
        const unsigned short* ev = reinterpret_cast<const unsigned short*>(&v0);
        const unsigned short* ov = reinterpret_cast<const unsigned short*>(&v1);
#pragma unroll
        for (int j = 0; j < 8; ++j)
            Vtp[(m0 + j) * PQ + sp] =
                (unsigned int)ev[j] | ((unsigned int)ov[j] << 16);
    }
    if (tid < DHEAD)
        zsh[tid] = Zx[((size_t)bh * NCHUNK + c) * DHEAD + tid];
    __syncthreads();

    const int wave = tid >> 6, lane = tid & 63;
    const int la = lane & 15, q = lane >> 4;
    const int wt = (wave >> 1) * 32, wn = (wave & 1) * 32;

    // phase 1: A = Q K^T (fragments: direct uint4 -> bf16x8)
    f32x4 acc[2][2];
#pragma unroll
    for (int i = 0; i < 2; ++i)
#pragma unroll
        for (int j = 0; j < 2; ++j) acc[i][j] = (f32x4){0.f, 0.f, 0.f, 0.f};
#pragma unroll
    for (int ks = 0; ks < 2; ++ks) {
        const int ku = ks * 16 + q * 4;                      // uint offset (k=d)
        const bf16x8 a0  = __builtin_bit_cast(bf16x8,
            *reinterpret_cast<const uint4*>(&Qp[(wt + la) * PQ + ku]));
        const bf16x8 a1  = __builtin_bit_cast(bf16x8,
            *reinterpret_cast<const uint4*>(&Qp[(wt + 16 + la) * PQ + ku]));
        const bf16x8 bb0 = __builtin_bit_cast(bf16x8,
            *reinterpret_cast<const uint4*>(&Kp[(wn + la) * PQ + ku]));
        const bf16x8 bb1 = __builtin_bit_cast(bf16x8,
            *reinterpret_cast<const uint4*>(&Kp[(wn + 16 + la) * PQ + ku]));
        acc[0][0] = __builtin_amdgcn_mfma_f32_16x16x32_bf16(a0, bb0, acc[0][0], 0, 0, 0);
        acc[0][1] = __builtin_amdgcn_mfma_f32_16x16x32_bf16(a0, bb1, acc[0][1], 0, 0, 0);
        acc[1][0] = __builtin_amdgcn_mfma_f32_16x16x32_bf16(a1, bb0, acc[1][0], 0, 0, 0);
        acc[1][1] = __builtin_amdgcn_mfma_f32_16x16x32_bf16(a1, bb1, acc[1][1], 0, 0, 0);
    }
#pragma unroll
    for (int mi = 0; mi < 2; ++mi)
#pragma unroll
        for (int ni = 0; ni < 2; ++ni) {
            const int t0 = wt + mi * 16 + q * 4;
            const int s  = wn + ni * 16 + la;
#pragma unroll
            for (int r = 0; r < 4; ++r)
                At[(t0 + r) * LSTRF + s] = (s <= t0 + r) ? acc[mi][ni][r] : 0.f;
        }
    __syncthreads();

    // phase 2: denom[t] = rowsum(A) + Q . Z_prev + eps  (Q via unpack2)
    if (tid < CHUNK) {
        float dv = 0.f;
        for (int s = 0; s < CHUNK; ++s) dv += At[tid * LSTRF + s];
        for (int dd = 0; dd < 32; ++dd) {
            float lo, hi;
            unpack2(Qp[tid * PQ + dd], lo, hi);
            dv = fmaf(lo, zsh[2 * dd], dv);
            dv = fmaf(hi, zsh[2 * dd + 1], dv);
        }
        dnm[tid] = dv + EPSV;
    }
    __syncthreads();

    // phase 3: O = Q @ S_prev + A @ V
    f32x4 o[2][2];
#pragma unroll
    for (int i = 0; i < 2; ++i)
#pragma unroll
        for (int j = 0; j < 2; ++j) o[i][j] = (f32x4){0.f, 0.f, 0.f, 0.f};
#pragma unroll
    for (int ks = 0; ks < 2; ++ks) {
        const int ku = ks * 16 + q * 4;                      // uint offset (k=d)
        const int ko = ks * 32 + q * 8;                      // elem offset
        const bf16x8 a0  = __builtin_bit_cast(bf16x8,
            *reinterpret_cast<const uint4*>(&Qp[(wt + la) * PQ + ku]));
        const bf16x8 a1  = __builtin_bit_cast(bf16x8,
            *reinterpret_cast<const uint4*>(&Qp[(wt + 16 + la) * PQ + ku]));
        const bf16x8 bb0 = frag8(&Pp[(wn + la) * DHEAD + ko]);        // global
        const bf16x8 bb1 = frag8(&Pp[(wn + 16 + la) * DHEAD + ko]);   // global
        o[0][0] = __builtin_amdgcn_mfma_f32_16x16x32_bf16(a0, bb0, o[0][0], 0, 0, 0);
        o[0][1] = __builtin_amdgcn_mfma_f32_16x16x32_bf16(a0, bb1, o[0][1], 0, 0, 0);
        o[1][0] = __builtin_amdgcn_mfma_f32_16x16x32_bf16(a1, bb0, o[1][0], 0, 0, 0);
        o[1][1] = __builtin_amdgcn_mfma_f32_16x16x32_bf16(a1, bb1, o[1][1], 0, 0, 0);
    }
#pragma unroll
    for (int ks = 0; ks < 2; ++ks) {
        const int ku = ks * 16 + q * 4;                      // uint offset (k=s)
        const int ko = ks * 32 + q * 8;
        const bf16x8 a0  = frag8(&At[(wt + la) * LSTRF + ko]);
        const bf16x8 a1  = frag8(&At[(wt + 16 + la) * LSTRF + ko]);
        const bf16x8 bb0 = __builtin_bit_cast(bf16x8,
            *reinterpret_cast<const uint4*>(&Vtp[(wn + la) * PQ + ku]));
        const bf16x8 bb1 = __builtin_bit_cast(bf16x8,
            *reinterpret_cast<const uint4*>(&Vtp[(wn + 16 + la) * PQ + ku]));
        o[0][0] = __builtin_amdgcn_mfma_f32_16x16x32_bf16(a0, bb0, o[0][0], 0, 0, 0);
        o[0][1] = __builtin_amdgcn_mfma_f32_16x16x32_bf16(a0, bb1, o[0][1], 0, 0, 0);
        o[1][0] = __builtin_amdgcn_mfma_f32_16x16x32_bf16(a1, bb0, o[1][0], 0, 0, 0);
        o[1][1] = __builtin_amdgcn_mfma_f32_16x16x32_bf16(a1, bb1, o[1][1], 0, 0, 0);
    }

    // epilogue: divide + bf16 scalar stores (verified class)
#pragma unroll
    for (int mi = 0; mi < 2; ++mi)
#pragma unroll
        for (int ni = 0; ni < 2; ++ni) {
            const int t0 = wt + mi * 16 + q * 4;
            const int m  = wn + ni * 16 + la;
#pragma unroll
            for (int r = 0; r < 4; ++r) {
                const float v = o[mi][ni][r] / dnm[t0 + r];
                Ob[gbase + (size_t)(t0 + r) * D_MODEL + m] = f2bf(v);
            }
        }
}

extern "C" void kernel_launch(void* const* d_in, const int* in_sizes, int n_in,
                              void* d_out, int out_size, void* d_ws, size_t ws_size,
                              hipStream_t stream)
{
    const float* x  = (const float*)d_in[0];
    const float* Wq = (const float*)d_in[1];
    const float* bq = (const float*)d_in[2];
    const float* Wk = (const float*)d_in[3];
    const float* bk = (const float*)d_in[4];
    const float* Wv = (const float*)d_in[5];
    const float* bv = (const float*)d_in[6];
    const float* Wo = (const float*)d_in[7];
    const float* bo = (const float*)d_in[8];
    float* out = (float*)d_out;

    const size_t NE = (size_t)NTOK * D_MODEL;               // 2M elems
    unsigned short* xb  = (unsigned short*)d_ws;            // 2M bf16
    unsigned short* Wt  = xb + NE;                          // 768*256
    unsigned short* Wot = Wt + 768 * 256;                   // 256*256
    unsigned short* Qb  = Wot + 256 * 256;                  // 2M
    unsigned short* Kb  = Qb + NE;                          // 2M
    unsigned short* Vb  = Kb + NE;                          // 2M
    unsigned short* Ob  = Vb + NE;                          // 2M
    float* P = (float*)(Ob + NE);                           // 16*32*4096 f32 (8MB)
    float* Z = P + (size_t)NBH * NCHUNK * DHEAD * DHEAD;    // 16*32*64 f32

    convert_kernel<<<NTOK * D_MODEL / 8 / 256 + 64, 256, 0, stream>>>(
        x, Wq, Wk, Wv, Wo, xb, Wt, Wot);
    mfma_gemm_kernel<0><<<(NTOK / 64) * 12, 256, 0, stream>>>(
        xb, Wt, bq, bk, bv, Qb, Kb, Vb);
    chunksum_kernel<<<NBH * NCHUNK, 256, 0, stream>>>(Kb, Vb, P, Z);
    prefix_kernel<<<NBH * 16 + 4, 256, 0, stream>>>(P, Z);
    chunkout_kernel<<<NBH * NCHUNK, 256, 0, stream>>>(Qb, Kb, Vb, P, Z, Ob);
    mfma_gemm_kernel<1><<<(NTOK / 64) * 4, 256, 0, stream>>>(
        Ob, Wot, bo, nullptr, nullptr, out, nullptr, nullptr);
}

// Round 17
// 106.400 us; speedup vs baseline: 4.0617x; 1.0277x over previous
//
#include <hip/hip_runtime.h>
#include <hip/hip_bf16.h>

#define D_MODEL 256
#define NHEADS 4
#define DHEAD 64
#define BATCH 4
#define TSEQ 2048
#define CHUNK 64
#define NCHUNK (TSEQ / CHUNK)   // 32
#define NTOK (BATCH * TSEQ)     // 8192
#define NBH (BATCH * NHEADS)    // 16
#define EPSV 1e-6f
#define LSTRF 68                // fp32 LDS row stride (verified)
#define PQ 36                   // packed-bf16 LDS row stride in uints (144B)

typedef __bf16 bf16x8 __attribute__((ext_vector_type(8)));
typedef float f32x4 __attribute__((ext_vector_type(4)));
typedef unsigned short us8 __attribute__((ext_vector_type(8)));

__device__ __forceinline__ float elu1(float a) {
    return a > 0.0f ? a + 1.0f : __expf(a);
}

__device__ __forceinline__ unsigned short f2bf(float f) {
    __hip_bfloat16 h = __float2bfloat16(f);   // RNE
    return __builtin_bit_cast(unsigned short, h);
}

__device__ __forceinline__ float bf2f(unsigned short u) {
    return __bfloat162float(__builtin_bit_cast(__hip_bfloat16, u));
}

// unpack a dword holding 2 bf16 (lo,hi) into 2 fp32 — 2 VALU ops
__device__ __forceinline__ void unpack2(unsigned int u, float& lo, float& hi) {
    lo = __builtin_bit_cast(float, u << 16);
    hi = __builtin_bit_cast(float, u & 0xFFFF0000u);
}

// Build a bf16x8 MFMA fragment from 8 consecutive fp32 (16B-aligned).
__device__ __forceinline__ bf16x8 frag8(const float* p) {
    const float4 x = *reinterpret_cast<const float4*>(p);
    const float4 y = *reinterpret_cast<const float4*>(p + 4);
    us8 u;
    u[0] = f2bf(x.x); u[1] = f2bf(x.y); u[2] = f2bf(x.z); u[3] = f2bf(x.w);
    u[4] = f2bf(y.x); u[5] = f2bf(y.y); u[6] = f2bf(y.z); u[7] = f2bf(y.w);
    return __builtin_bit_cast(bf16x8, u);
}

// async global->LDS, 16B per lane; lds ptr must be wave-uniform base.
__device__ __forceinline__ void gld_lds16(const void* g, void* l) {
    __builtin_amdgcn_global_load_lds(
        (const __attribute__((address_space(1))) void*)g,
        (__attribute__((address_space(3))) void*)l, 16, 0, 0);
}

// ---------------------------------------------------------------------------
// fused converts (R12/R16-verified): blocks [0,1024): x->bf16; rest: W^T
// ---------------------------------------------------------------------------
__global__ __launch_bounds__(256) void convert_kernel(
    const float* __restrict__ x,
    const float* __restrict__ Wq, const float* __restrict__ Wk,
    const float* __restrict__ Wv, const float* __restrict__ Wo,
    unsigned short* __restrict__ xb,
    unsigned short* __restrict__ Wt, unsigned short* __restrict__ Wot)
{
    const int tid = threadIdx.x;
    if (blockIdx.x < NTOK * D_MODEL / 8 / 256) {
        const int i = (blockIdx.x * 256 + tid) * 8;
        const float4 a = *reinterpret_cast<const float4*>(&x[i]);
        const float4 b = *reinterpret_cast<const float4*>(&x[i + 4]);
        ushort4 u0 = { f2bf(a.x), f2bf(a.y), f2bf(a.z), f2bf(a.w) };
        ushort4 u1 = { f2bf(b.x), f2bf(b.y), f2bf(b.z), f2bf(b.w) };
        *reinterpret_cast<ushort4*>(&xb[i]) = u0;
        *reinterpret_cast<ushort4*>(&xb[i + 4]) = u1;
        return;
    }
    __shared__ float Ls[64][65];
    const int bid = blockIdx.x - NTOK * D_MODEL / 8 / 256;
    const int wi = bid >> 4;
    const int ti = bid & 15;
    const int k0 = (ti >> 2) * 64, n0 = (ti & 3) * 64;
    const float* W = wi == 0 ? Wq : wi == 1 ? Wk : wi == 2 ? Wv : Wo;
#pragma unroll
    for (int i = 0; i < 16; ++i) {
        const int idx = i * 256 + tid;
        const int r = idx >> 6, c = idx & 63;
        Ls[r][c] = W[(size_t)(k0 + r) * D_MODEL + n0 + c];
    }
    __syncthreads();
    unsigned short* outp = (wi < 3) ? (Wt + (size_t)(wi * 256 + n0) * D_MODEL + k0)
                                    : (Wot + (size_t)n0 * D_MODEL + k0);
#pragma unroll
    for (int i = 0; i < 16; ++i) {
        const int idx = i * 256 + tid;
        const int rn = idx >> 6, ck = idx & 63;
        outp[(size_t)rn * D_MODEL + ck] = f2bf(Ls[ck][rn]);
    }
}

// ---------------------------------------------------------------------------
// MFMA bf16 GEMM — 64x64 tile (R12/R16-verified).
// MODE 0: qkv; elu1 on Q,K; bf16 out.  MODE 1: ogemm; fp32 out.
// ---------------------------------------------------------------------------
template<int MODE>
__global__ __launch_bounds__(256) void mfma_gemm_kernel(
    const unsigned short* __restrict__ A,
    const unsigned short* __restrict__ Bt,
    const float* __restrict__ b0, const float* __restrict__ b1,
    const float* __restrict__ b2,
    void* __restrict__ O0, void* __restrict__ O1, void* __restrict__ O2)
{
    __shared__ __align__(16) unsigned short As[64 * 64];
    __shared__ __align__(16) unsigned short Bs[64 * 64];
    const int tid = threadIdx.x;
    const int wave = tid >> 6, lane = tid & 63;
    const int la = lane & 15, q = lane >> 4;

    int mtile, ntile;
    if (MODE == 0) { ntile = blockIdx.x % 12; mtile = blockIdx.x / 12; }
    else           { ntile = blockIdx.x & 3;  mtile = blockIdx.x >> 2; }
    const int m0 = mtile * 64, n0 = ntile * 64;

    const unsigned short* Ab = A  + (size_t)m0 * D_MODEL;
    const unsigned short* Bb = Bt + (size_t)n0 * D_MODEL;

    f32x4 acc[4];
#pragma unroll
    for (int i = 0; i < 4; ++i) acc[i] = (f32x4){0.f, 0.f, 0.f, 0.f};

    for (int k0 = 0; k0 < D_MODEL; k0 += 64) {
#pragma unroll
        for (int i = 0; i < 2; ++i) {
            const int bslot = i * 256 + wave * 64;   // wave-uniform base
            const int slot = bslot + lane;
            const int m = slot >> 3, s = slot & 7;
            const int g = s ^ (m & 7);
            gld_lds16(Ab + (size_t)m * D_MODEL + k0 + g * 8, &As[bslot * 8]);
            gld_lds16(Bb + (size_t)m * D_MODEL + k0 + g * 8, &Bs[bslot * 8]);
        }
        __syncthreads();

        bf16x8 af[2], bfr[4][2];
#pragma unroll
        for (int kh = 0; kh < 2; ++kh) {
            const int g = kh * 4 + q;
            const int m = wave * 16 + la;
            af[kh] = *reinterpret_cast<const bf16x8*>(
                &As[m * 64 + ((g ^ (m & 7)) << 3)]);
#pragma unroll
            for (int ni = 0; ni < 4; ++ni) {
                const int n = ni * 16 + la;
                bfr[ni][kh] = *reinterpret_cast<const bf16x8*>(
                    &Bs[n * 64 + ((g ^ (n & 7)) << 3)]);
            }
        }
#pragma unroll
        for (int ni = 0; ni < 4; ++ni) {
            acc[ni] = __builtin_amdgcn_mfma_f32_16x16x32_bf16(
                af[0], bfr[ni][0], acc[ni], 0, 0, 0);
            acc[ni] = __builtin_amdgcn_mfma_f32_16x16x32_bf16(
                af[1], bfr[ni][1], acc[ni], 0, 0, 0);
        }
        __syncthreads();
    }

    // C/D layout: col=lane&15, row=(lane>>4)*4+reg
#pragma unroll
    for (int ni = 0; ni < 4; ++ni) {
        const int row = m0 + wave * 16 + q * 4;
        const int col = n0 + ni * 16 + la;
        if (MODE == 0) {
            const int which = col >> 8;          // block-uniform
            const int cl = col & 255;
            unsigned short* Out = (unsigned short*)
                (which == 0 ? O0 : which == 1 ? O1 : O2);
            const float* bias = which == 0 ? b0 : which == 1 ? b1 : b2;
            const int act = (which < 2);
            const float bv = bias[cl];
#pragma unroll
            for (int r = 0; r < 4; ++r) {
                float v = acc[ni][r] + bv;
                if (act) v = elu1(v);
                Out[(size_t)(row + r) * D_MODEL + cl] = f2bf(v);
            }
        } else {
            float* Out = (float*)O0;
            const float bv = b0[col];
#pragma unroll
            for (int r = 0; r < 4; ++r)
                Out[(size_t)(row + r) * D_MODEL + col] = acc[ni][r] + bv;
        }
    }
}

// ---------------------------------------------------------------------------
// chunksum — NEW: packed-bf16 LDS (R16 pattern). Pt_c[m][d] = sum_t V[t][m]K[t][d].
// Staging: uint4 row loads + pack-pair b32 scatter (exact R16 V pattern).
// Fragments: direct uint4 -> bf16x8 (k = t). Z unpacks in t-order (bit-identical).
// ---------------------------------------------------------------------------
__global__ __launch_bounds__(256) void chunksum_kernel(
    const unsigned short* __restrict__ Kb, const unsigned short* __restrict__ Vb,
    float* __restrict__ Pt, float* __restrict__ Zc)
{
    __shared__ __align__(16) unsigned int Ktp[DHEAD * PQ];  // [d][t/2]
    __shared__ __align__(16) unsigned int Vtp[DHEAD * PQ];  // [m][t/2]
    const int tid = threadIdx.x;
    const int c  = blockIdx.x % NCHUNK;
    const int bh = blockIdx.x / NCHUNK;
    const int b = bh / NHEADS, h = bh % NHEADS;
    const size_t gbase = ((size_t)(b * TSEQ + c * CHUNK)) * D_MODEL + h * DHEAD;

    // staging: thread = (t-pair sp, 8 elems at e0)
    {
        const int sp = tid & 31, mg = tid >> 5;
        const int e0 = mg * 8;
        const uint4 k0 = *reinterpret_cast<const uint4*>(
            &Kb[gbase + (size_t)(2 * sp) * D_MODEL + e0]);
        const uint4 k1 = *reinterpret_cast<const uint4*>(
            &Kb[gbase + (size_t)(2 * sp + 1) * D_MODEL + e0]);
        const uint4 v0 = *reinterpret_cast<const uint4*>(
            &Vb[gbase + (size_t)(2 * sp) * D_MODEL + e0]);
        const uint4 v1 = *reinterpret_cast<const uint4*>(
            &Vb[gbase + (size_t)(2 * sp + 1) * D_MODEL + e0]);
        const unsigned short* ke = reinterpret_cast<const unsigned short*>(&k0);
        const unsigned short* ko2 = reinterpret_cast<const unsigned short*>(&k1);
        const unsigned short* ve = reinterpret_cast<const unsigned short*>(&v0);
        const unsigned short* vo = reinterpret_cast<const unsigned short*>(&v1);
#pragma unroll
        for (int j = 0; j < 8; ++j) {
            Ktp[(e0 + j) * PQ + sp] =
                (unsigned int)ke[j] | ((unsigned int)ko2[j] << 16);
            Vtp[(e0 + j) * PQ + sp] =
                (unsigned int)ve[j] | ((unsigned int)vo[j] << 16);
        }
    }
    __syncthreads();

    const int wave = tid >> 6, lane = tid & 63;
    const int la = lane & 15, q = lane >> 4;
    const int wm = (wave >> 1) * 32, wn = (wave & 1) * 32;   // m rows, d cols

    f32x4 acc[2][2];
#pragma unroll
    for (int i = 0; i < 2; ++i)
#pragma unroll
        for (int j = 0; j < 2; ++j) acc[i][j] = (f32x4){0.f, 0.f, 0.f, 0.f};

#pragma unroll
    for (int ks = 0; ks < 2; ++ks) {
        const int ku = ks * 16 + q * 4;                      // uint offset (k=t)
        const bf16x8 a0  = __builtin_bit_cast(bf16x8,
            *reinterpret_cast<const uint4*>(&Vtp[(wm + la) * PQ + ku]));
        const bf16x8 a1  = __builtin_bit_cast(bf16x8,
            *reinterpret_cast<const uint4*>(&Vtp[(wm + 16 + la) * PQ + ku]));
        const bf16x8 bb0 = __builtin_bit_cast(bf16x8,
            *reinterpret_cast<const uint4*>(&Ktp[(wn + la) * PQ + ku]));
        const bf16x8 bb1 = __builtin_bit_cast(bf16x8,
            *reinterpret_cast<const uint4*>(&Ktp[(wn + 16 + la) * PQ + ku]));
        acc[0][0] = __builtin_amdgcn_mfma_f32_16x16x32_bf16(a0, bb0, acc[0][0], 0, 0, 0);
        acc[0][1] = __builtin_amdgcn_mfma_f32_16x16x32_bf16(a0, bb1, acc[0][1], 0, 0, 0);
        acc[1][0] = __builtin_amdgcn_mfma_f32_16x16x32_bf16(a1, bb0, acc[1][0], 0, 0, 0);
        acc[1][1] = __builtin_amdgcn_mfma_f32_16x16x32_bf16(a1, bb1, acc[1][1], 0, 0, 0);
    }

    float* Pb = Pt + (size_t)blockIdx.x * (DHEAD * DHEAD);
#pragma unroll
    for (int mi = 0; mi < 2; ++mi)
#pragma unroll
        for (int ni = 0; ni < 2; ++ni) {
            const int row = wm + mi * 16 + q * 4;   // m
            const int col = wn + ni * 16 + la;      // d
#pragma unroll
            for (int r = 0; r < 4; ++r)
                Pb[(row + r) * DHEAD + col] = acc[mi][ni][r];
        }

    if (tid < DHEAD) {
        float z = 0.f;
        for (int tt = 0; tt < 32; ++tt) {
            float lo, hi;
            unpack2(Ktp[tid * PQ + tt], lo, hi);
            z += lo;
            z += hi;
        }
        Zc[(size_t)blockIdx.x * DHEAD + tid] = z;
    }
}

// ---------------------------------------------------------------------------
// prefix — exclusive scan (R12-verified) + NEW: emit packed-bf16 Sb of the
// exclusive sums (same fp32 values chunkout used to convert itself).
// ---------------------------------------------------------------------------
__global__ __launch_bounds__(256) void prefix_kernel(
    float* __restrict__ P, float* __restrict__ Zc,
    unsigned short* __restrict__ Sb)
{
    const int tid = threadIdx.x;
    if (blockIdx.x < NBH * 16) {
        const int bh = blockIdx.x >> 4;
        const int e = ((blockIdx.x & 15) << 8) + tid;
        const size_t base = (size_t)bh * NCHUNK * (DHEAD * DHEAD) + e;
        float v[NCHUNK];
#pragma unroll
        for (int c = 0; c < NCHUNK; ++c) v[c] = P[base + (size_t)c * (DHEAD * DHEAD)];
        float s = 0.f;
#pragma unroll
        for (int c = 0; c < NCHUNK; ++c) {
            const float t = v[c];
            Sb[base + (size_t)c * (DHEAD * DHEAD)] = f2bf(s);
            s += t;
        }
    } else {
        const int j = ((int)(blockIdx.x - NBH * 16) << 8) + tid;
        if (j < NBH * DHEAD) {
            const int bh = j >> 6, d = j & 63;
            float v[NCHUNK];
#pragma unroll
            for (int c = 0; c < NCHUNK; ++c) v[c] = Zc[(bh * NCHUNK + c) * DHEAD + d];
            float s = 0.f;
#pragma unroll
            for (int c = 0; c < NCHUNK; ++c) {
                const float t = v[c];
                Zc[(bh * NCHUNK + c) * DHEAD + d] = s;
                s += t;
            }
        }
    }
}

// ---------------------------------------------------------------------------
// chunkout (R16-verified packed LDS) — NEW: S_prev B-frags read as uint4
// from packed-bf16 Sb (global) instead of frag8 over fp32 P.
// ---------------------------------------------------------------------------
__global__ __launch_bounds__(256) void chunkout_kernel(
    const unsigned short* __restrict__ Qb, const unsigned short* __restrict__ Kb,
    const unsigned short* __restrict__ Vb,
    const unsigned short* __restrict__ Sb, const float* __restrict__ Zx,
    unsigned short* __restrict__ Ob)
{
    __shared__ __align__(16) unsigned int Qp[CHUNK * PQ];   // packed [t][d/2]
    __shared__ __align__(16) unsigned int Kp[CHUNK * PQ];   // packed [s][d/2]
    __shared__ __align__(16) unsigned int Vtp[DHEAD * PQ];  // packed [m][s/2]
    __shared__ __align__(16) float At[CHUNK * LSTRF];       // fp32 [t][s]
    __shared__ float zsh[DHEAD];
    __shared__ float dnm[CHUNK];

    const int tid = threadIdx.x;
    const int c  = blockIdx.x % NCHUNK;
    const int bh = blockIdx.x / NCHUNK;
    const int b = bh / NHEADS, h = bh % NHEADS;
    const size_t gbase = ((size_t)(b * TSEQ + c * CHUNK)) * D_MODEL + h * DHEAD;
    const unsigned short* Sp = Sb + (size_t)blockIdx.x * (DHEAD * DHEAD);

    // stage Q,K: straight packed 16B copies (no conversion)
#pragma unroll
    for (int i = 0; i < 2; ++i) {
        const int idx = i * 256 + tid;           // 0..511
        const int t = idx >> 3, e4 = (idx & 7) * 4;   // uint offset in row
        const uint4 qv = *reinterpret_cast<const uint4*>(
            &Qb[gbase + (size_t)t * D_MODEL + e4 * 2]);
        const uint4 kv = *reinterpret_cast<const uint4*>(
            &Kb[gbase + (size_t)t * D_MODEL + e4 * 2]);
        *reinterpret_cast<uint4*>(&Qp[t * PQ + e4]) = qv;
        *reinterpret_cast<uint4*>(&Kp[t * PQ + e4]) = kv;
    }
    // stage V transposed, packed along s: thread = (s-pair, 8 m's)
    {
        const int sp = tid & 31, mg = tid >> 5;
        const int m0 = mg * 8;
        const uint4 v0 = *reinterpret_cast<const uint4*>(
            &Vb[gbase + (size_t)(2 * sp) * D_MODEL + m0]);
        const uint4 v1 = *reinterpret_cast<const uint4*>(
            &Vb[gbase + (size_t)(2 * sp + 1) * D_MODEL + m0]);
        const unsigned short* ev = reinterpret_cast<const unsigned short*>(&v0);
        const unsigned short* ov = reinterpret_cast<const unsigned short*>(&v1);
#pragma unroll
        for (int j = 0; j < 8; ++j)
            Vtp[(m0 + j) * PQ + sp] =
                (unsigned int)ev[j] | ((unsigned int)ov[j] << 16);
    }
    if (tid < DHEAD)
        zsh[tid] = Zx[((size_t)bh * NCHUNK + c) * DHEAD + tid];
    __syncthreads();

    const int wave = tid >> 6, lane = tid & 63;
    const int la = lane & 15, q = lane >> 4;
    const int wt = (wave >> 1) * 32, wn = (wave & 1) * 32;

    // phase 1: A = Q K^T
    f32x4 acc[2][2];
#pragma unroll
    for (int i = 0; i < 2; ++i)
#pragma unroll
        for (int j = 0; j < 2; ++j) acc[i][j] = (f32x4){0.f, 0.f, 0.f, 0.f};
#pragma unroll
    for (int ks = 0; ks < 2; ++ks) {
        const int ku = ks * 16 + q * 4;                      // uint offset (k=d)
        const bf16x8 a0  = __builtin_bit_cast(bf16x8,
            *reinterpret_cast<const uint4*>(&Qp[(wt + la) * PQ + ku]));
        const bf16x8 a1  = __builtin_bit_cast(bf16x8,
            *reinterpret_cast<const uint4*>(&Qp[(wt + 16 + la) * PQ + ku]));
        const bf16x8 bb0 = __builtin_bit_cast(bf16x8,
            *reinterpret_cast<const uint4*>(&Kp[(wn + la) * PQ + ku]));
        const bf16x8 bb1 = __builtin_bit_cast(bf16x8,
            *reinterpret_cast<const uint4*>(&Kp[(wn + 16 + la) * PQ + ku]));
        acc[0][0] = __builtin_amdgcn_mfma_f32_16x16x32_bf16(a0, bb0, acc[0][0], 0, 0, 0);
        acc[0][1] = __builtin_amdgcn_mfma_f32_16x16x32_bf16(a0, bb1, acc[0][1], 0, 0, 0);
        acc[1][0] = __builtin_amdgcn_mfma_f32_16x16x32_bf16(a1, bb0, acc[1][0], 0, 0, 0);
        acc[1][1] = __builtin_amdgcn_mfma_f32_16x16x32_bf16(a1, bb1, acc[1][1], 0, 0, 0);
    }
#pragma unroll
    for (int mi = 0; mi < 2; ++mi)
#pragma unroll
        for (int ni = 0; ni < 2; ++ni) {
            const int t0 = wt + mi * 16 + q * 4;
            const int s  = wn + ni * 16 + la;
#pragma unroll
            for (int r = 0; r < 4; ++r)
                At[(t0 + r) * LSTRF + s] = (s <= t0 + r) ? acc[mi][ni][r] : 0.f;
        }
    __syncthreads();

    // phase 2: denom[t] = rowsum(A) + Q . Z_prev + eps  (Q via unpack2)
    if (tid < CHUNK) {
        float dv = 0.f;
        for (int s = 0; s < CHUNK; ++s) dv += At[tid * LSTRF + s];
        for (int dd = 0; dd < 32; ++dd) {
            float lo, hi;
            unpack2(Qp[tid * PQ + dd], lo, hi);
            dv = fmaf(lo, zsh[2 * dd], dv);
            dv = fmaf(hi, zsh[2 * dd + 1], dv);
        }
        dnm[tid] = dv + EPSV;
    }
    __syncthreads();

    // phase 3: O = Q @ S_prev + A @ V
    f32x4 o[2][2];
#pragma unroll
    for (int i = 0; i < 2; ++i)
#pragma unroll
        for (int j = 0; j < 2; ++j) o[i][j] = (f32x4){0.f, 0.f, 0.f, 0.f};
#pragma unroll
    for (int ks = 0; ks < 2; ++ks) {
        const int ku = ks * 16 + q * 4;                      // uint offset (k=d)
        const int ko = ks * 32 + q * 8;                      // elem offset
        const bf16x8 a0  = __builtin_bit_cast(bf16x8,
            *reinterpret_cast<const uint4*>(&Qp[(wt + la) * PQ + ku]));
        const bf16x8 a1  = __builtin_bit_cast(bf16x8,
            *reinterpret_cast<const uint4*>(&Qp[(wt + 16 + la) * PQ + ku]));
        const bf16x8 bb0 = __builtin_bit_cast(bf16x8,
            *reinterpret_cast<const uint4*>(&Sp[(wn + la) * DHEAD + ko]));      // global, packed
        const bf16x8 bb1 = __builtin_bit_cast(bf16x8,
            *reinterpret_cast<const uint4*>(&Sp[(wn + 16 + la) * DHEAD + ko])); // global, packed
        o[0][0] = __builtin_amdgcn_mfma_f32_16x16x32_bf16(a0, bb0, o[0][0], 0, 0, 0);
        o[0][1] = __builtin_amdgcn_mfma_f32_16x16x32_bf16(a0, bb1, o[0][1], 0, 0, 0);
        o[1][0] = __builtin_amdgcn_mfma_f32_16x16x32_bf16(a1, bb0, o[1][0], 0, 0, 0);
        o[1][1] = __builtin_amdgcn_mfma_f32_16x16x32_bf16(a1, bb1, o[1][1], 0, 0, 0);
    }
#pragma unroll
    for (int ks = 0; ks < 2; ++ks) {
        const int ku = ks * 16 + q * 4;                      // uint offset (k=s)
        const int ko = ks * 32 + q * 8;
        const bf16x8 a0  = frag8(&At[(wt + la) * LSTRF + ko]);
        const bf16x8 a1  = frag8(&At[(wt + 16 + la) * LSTRF + ko]);
        const bf16x8 bb0 = __builtin_bit_cast(bf16x8,
            *reinterpret_cast<const uint4*>(&Vtp[(wn + la) * PQ + ku]));
        const bf16x8 bb1 = __builtin_bit_cast(bf16x8,
            *reinterpret_cast<const uint4*>(&Vtp[(wn + 16 + la) * PQ + ku]));
        o[0][0] = __builtin_amdgcn_mfma_f32_16x16x32_bf16(a0, bb0, o[0][0], 0, 0, 0);
        o[0][1] = __builtin_amdgcn_mfma_f32_16x16x32_bf16(a0, bb1, o[0][1], 0, 0, 0);
        o[1][0] = __builtin_amdgcn_mfma_f32_16x16x32_bf16(a1, bb0, o[1][0], 0, 0, 0);
        o[1][1] = __builtin_amdgcn_mfma_f32_16x16x32_bf16(a1, bb1, o[1][1], 0, 0, 0);
    }

    // epilogue: divide + bf16 scalar stores (verified class)
#pragma unroll
    for (int mi = 0; mi < 2; ++mi)
#pragma unroll
        for (int ni = 0; ni < 2; ++ni) {
            const int t0 = wt + mi * 16 + q * 4;
            const int m  = wn + ni * 16 + la;
#pragma unroll
            for (int r = 0; r < 4; ++r) {
                const float v = o[mi][ni][r] / dnm[t0 + r];
                Ob[gbase + (size_t)(t0 + r) * D_MODEL + m] = f2bf(v);
            }
        }
}

extern "C" void kernel_launch(void* const* d_in, const int* in_sizes, int n_in,
                              void* d_out, int out_size, void* d_ws, size_t ws_size,
                              hipStream_t stream)
{
    const float* x  = (const float*)d_in[0];
    const float* Wq = (const float*)d_in[1];
    const float* bq = (const float*)d_in[2];
    const float* Wk = (const float*)d_in[3];
    const float* bk = (const float*)d_in[4];
    const float* Wv = (const float*)d_in[5];
    const float* bv = (const float*)d_in[6];
    const float* Wo = (const float*)d_in[7];
    const float* bo = (const float*)d_in[8];
    float* out = (float*)d_out;

    const size_t NE = (size_t)NTOK * D_MODEL;               // 2M elems
    const size_t PE = (size_t)NBH * NCHUNK * DHEAD * DHEAD; // 2M elems
    unsigned short* xb  = (unsigned short*)d_ws;            // 2M bf16
    unsigned short* Wt  = xb + NE;                          // 768*256
    unsigned short* Wot = Wt + 768 * 256;                   // 256*256
    unsigned short* Qb  = Wot + 256 * 256;                  // 2M
    unsigned short* Kb  = Qb + NE;                          // 2M
    unsigned short* Vb  = Kb + NE;                          // 2M
    unsigned short* Ob  = Vb + NE;                          // 2M
    unsigned short* Sb  = Ob + NE;                          // 2M bf16 (4MB)
    float* P = (float*)(Sb + PE);                           // 2M f32 (8MB)
    float* Z = P + PE;                                      // 16*32*64 f32

    convert_kernel<<<NTOK * D_MODEL / 8 / 256 + 64, 256, 0, stream>>>(
        x, Wq, Wk, Wv, Wo, xb, Wt, Wot);
    mfma_gemm_kernel<0><<<(NTOK / 64) * 12, 256, 0, stream>>>(
        xb, Wt, bq, bk, bv, Qb, Kb, Vb);
    chunksum_kernel<<<NBH * NCHUNK, 256, 0, stream>>>(Kb, Vb, P, Z);
    prefix_kernel<<<NBH * 16 + 4, 256, 0, stream>>>(P, Z, Sb);
    chunkout_kernel<<<NBH * NCHUNK, 256, 0, stream>>>(Qb, Kb, Vb, Sb, Z, Ob);
    mfma_gemm_kernel<1><<<(NTOK / 64) * 4, 256, 0, stream>>>(
        Ob, Wot, bo, nullptr, nullptr, out, nullptr, nullptr);
}

// Round 18
// 104.607 us; speedup vs baseline: 4.1313x; 1.0171x over previous
//
#include <hip/hip_runtime.h>
#include <hip/hip_bf16.h>

#define D_MODEL 256
#define NHEADS 4
#define DHEAD 64
#define BATCH 4
#define TSEQ 2048
#define CHUNK 64
#define NCHUNK (TSEQ / CHUNK)   // 32
#define NTOK (BATCH * TSEQ)     // 8192
#define NBH (BATCH * NHEADS)    // 16
#define EPSV 1e-6f
#define LSTRF 68                // fp32 LDS row stride (verified)
#define PQ 36                   // packed-bf16 LDS row stride in uints (144B)

typedef __bf16 bf16x8 __attribute__((ext_vector_type(8)));
typedef float f32x4 __attribute__((ext_vector_type(4)));
typedef unsigned short us8 __attribute__((ext_vector_type(8)));

__device__ __forceinline__ float elu1(float a) {
    return a > 0.0f ? a + 1.0f : __expf(a);
}

__device__ __forceinline__ unsigned short f2bf(float f) {
    __hip_bfloat16 h = __float2bfloat16(f);   // RNE
    return __builtin_bit_cast(unsigned short, h);
}

__device__ __forceinline__ float bf2f(unsigned short u) {
    return __bfloat162float(__builtin_bit_cast(__hip_bfloat16, u));
}

// unpack a dword holding 2 bf16 (lo,hi) into 2 fp32 — 2 VALU ops
__device__ __forceinline__ void unpack2(unsigned int u, float& lo, float& hi) {
    lo = __builtin_bit_cast(float, u << 16);
    hi = __builtin_bit_cast(float, u & 0xFFFF0000u);
}

// Build a bf16x8 MFMA fragment from 8 consecutive fp32 (16B-aligned).
__device__ __forceinline__ bf16x8 frag8(const float* p) {
    const float4 x = *reinterpret_cast<const float4*>(p);
    const float4 y = *reinterpret_cast<const float4*>(p + 4);
    us8 u;
    u[0] = f2bf(x.x); u[1] = f2bf(x.y); u[2] = f2bf(x.z); u[3] = f2bf(x.w);
    u[4] = f2bf(y.x); u[5] = f2bf(y.y); u[6] = f2bf(y.z); u[7] = f2bf(y.w);
    return __builtin_bit_cast(bf16x8, u);
}

// async global->LDS, 16B per lane; lds ptr must be wave-uniform base.
__device__ __forceinline__ void gld_lds16(const void* g, void* l) {
    __builtin_amdgcn_global_load_lds(
        (const __attribute__((address_space(1))) void*)g,
        (__attribute__((address_space(3))) void*)l, 16, 0, 0);
}

// ---------------------------------------------------------------------------
// fused converts (R12/R16/R17-verified): blocks [0,1024): x->bf16; rest: W^T
// ---------------------------------------------------------------------------
__global__ __launch_bounds__(256) void convert_kernel(
    const float* __restrict__ x,
    const float* __restrict__ Wq, const float* __restrict__ Wk,
    const float* __restrict__ Wv, const float* __restrict__ Wo,
    unsigned short* __restrict__ xb,
    unsigned short* __restrict__ Wt, unsigned short* __restrict__ Wot)
{
    const int tid = threadIdx.x;
    if (blockIdx.x < NTOK * D_MODEL / 8 / 256) {
        const int i = (blockIdx.x * 256 + tid) * 8;
        const float4 a = *reinterpret_cast<const float4*>(&x[i]);
        const float4 b = *reinterpret_cast<const float4*>(&x[i + 4]);
        ushort4 u0 = { f2bf(a.x), f2bf(a.y), f2bf(a.z), f2bf(a.w) };
        ushort4 u1 = { f2bf(b.x), f2bf(b.y), f2bf(b.z), f2bf(b.w) };
        *reinterpret_cast<ushort4*>(&xb[i]) = u0;
        *reinterpret_cast<ushort4*>(&xb[i + 4]) = u1;
        return;
    }
    __shared__ float Ls[64][65];
    const int bid = blockIdx.x - NTOK * D_MODEL / 8 / 256;
    const int wi = bid >> 4;
    const int ti = bid & 15;
    const int k0 = (ti >> 2) * 64, n0 = (ti & 3) * 64;
    const float* W = wi == 0 ? Wq : wi == 1 ? Wk : wi == 2 ? Wv : Wo;
#pragma unroll
    for (int i = 0; i < 16; ++i) {
        const int idx = i * 256 + tid;
        const int r = idx >> 6, c = idx & 63;
        Ls[r][c] = W[(size_t)(k0 + r) * D_MODEL + n0 + c];
    }
    __syncthreads();
    unsigned short* outp = (wi < 3) ? (Wt + (size_t)(wi * 256 + n0) * D_MODEL + k0)
                                    : (Wot + (size_t)n0 * D_MODEL + k0);
#pragma unroll
    for (int i = 0; i < 16; ++i) {
        const int idx = i * 256 + tid;
        const int rn = idx >> 6, ck = idx & 63;
        outp[(size_t)rn * D_MODEL + ck] = f2bf(Ls[ck][rn]);
    }
}

// ---------------------------------------------------------------------------
// MFMA bf16 GEMM — 64x64 tile (R12/R16/R17-verified).
// MODE 0: qkv; elu1 on Q,K; bf16 out.  MODE 1: ogemm; fp32 out.
// ---------------------------------------------------------------------------
template<int MODE>
__global__ __launch_bounds__(256) void mfma_gemm_kernel(
    const unsigned short* __restrict__ A,
    const unsigned short* __restrict__ Bt,
    const float* __restrict__ b0, const float* __restrict__ b1,
    const float* __restrict__ b2,
    void* __restrict__ O0, void* __restrict__ O1, void* __restrict__ O2)
{
    __shared__ __align__(16) unsigned short As[64 * 64];
    __shared__ __align__(16) unsigned short Bs[64 * 64];
    const int tid = threadIdx.x;
    const int wave = tid >> 6, lane = tid & 63;
    const int la = lane & 15, q = lane >> 4;

    int mtile, ntile;
    if (MODE == 0) { ntile = blockIdx.x % 12; mtile = blockIdx.x / 12; }
    else           { ntile = blockIdx.x & 3;  mtile = blockIdx.x >> 2; }
    const int m0 = mtile * 64, n0 = ntile * 64;

    const unsigned short* Ab = A  + (size_t)m0 * D_MODEL;
    const unsigned short* Bb = Bt + (size_t)n0 * D_MODEL;

    f32x4 acc[4];
#pragma unroll
    for (int i = 0; i < 4; ++i) acc[i] = (f32x4){0.f, 0.f, 0.f, 0.f};

    for (int k0 = 0; k0 < D_MODEL; k0 += 64) {
#pragma unroll
        for (int i = 0; i < 2; ++i) {
            const int bslot = i * 256 + wave * 64;   // wave-uniform base
            const int slot = bslot + lane;
            const int m = slot >> 3, s = slot & 7;
            const int g = s ^ (m & 7);
            gld_lds16(Ab + (size_t)m * D_MODEL + k0 + g * 8, &As[bslot * 8]);
            gld_lds16(Bb + (size_t)m * D_MODEL + k0 + g * 8, &Bs[bslot * 8]);
        }
        __syncthreads();

        bf16x8 af[2], bfr[4][2];
#pragma unroll
        for (int kh = 0; kh < 2; ++kh) {
            const int g = kh * 4 + q;
            const int m = wave * 16 + la;
            af[kh] = *reinterpret_cast<const bf16x8*>(
                &As[m * 64 + ((g ^ (m & 7)) << 3)]);
#pragma unroll
            for (int ni = 0; ni < 4; ++ni) {
                const int n = ni * 16 + la;
                bfr[ni][kh] = *reinterpret_cast<const bf16x8*>(
                    &Bs[n * 64 + ((g ^ (n & 7)) << 3)]);
            }
        }
#pragma unroll
        for (int ni = 0; ni < 4; ++ni) {
            acc[ni] = __builtin_amdgcn_mfma_f32_16x16x32_bf16(
                af[0], bfr[ni][0], acc[ni], 0, 0, 0);
            acc[ni] = __builtin_amdgcn_mfma_f32_16x16x32_bf16(
                af[1], bfr[ni][1], acc[ni], 0, 0, 0);
        }
        __syncthreads();
    }

    // C/D layout: col=lane&15, row=(lane>>4)*4+reg
#pragma unroll
    for (int ni = 0; ni < 4; ++ni) {
        const int row = m0 + wave * 16 + q * 4;
        const int col = n0 + ni * 16 + la;
        if (MODE == 0) {
            const int which = col >> 8;          // block-uniform
            const int cl = col & 255;
            unsigned short* Out = (unsigned short*)
                (which == 0 ? O0 : which == 1 ? O1 : O2);
            const float* bias = which == 0 ? b0 : which == 1 ? b1 : b2;
            const int act = (which < 2);
            const float bv = bias[cl];
#pragma unroll
            for (int r = 0; r < 4; ++r) {
                float v = acc[ni][r] + bv;
                if (act) v = elu1(v);
                Out[(size_t)(row + r) * D_MODEL + cl] = f2bf(v);
            }
        } else {
            float* Out = (float*)O0;
            const float bv = b0[col];
#pragma unroll
            for (int r = 0; r < 4; ++r)
                Out[(size_t)(row + r) * D_MODEL + col] = acc[ni][r] + bv;
        }
    }
}

// ---------------------------------------------------------------------------
// chunksum (R17-verified packed staging) — NEW: P emitted as bf16 (scalar
// ushort stores, same class as chunkout's Ob epilogue). Halves P write bytes.
// ---------------------------------------------------------------------------
__global__ __launch_bounds__(256) void chunksum_kernel(
    const unsigned short* __restrict__ Kb, const unsigned short* __restrict__ Vb,
    unsigned short* __restrict__ Pb16, float* __restrict__ Zc)
{
    __shared__ __align__(16) unsigned int Ktp[DHEAD * PQ];  // [d][t/2]
    __shared__ __align__(16) unsigned int Vtp[DHEAD * PQ];  // [m][t/2]
    const int tid = threadIdx.x;
    const int c  = blockIdx.x % NCHUNK;
    const int bh = blockIdx.x / NCHUNK;
    const int b = bh / NHEADS, h = bh % NHEADS;
    const size_t gbase = ((size_t)(b * TSEQ + c * CHUNK)) * D_MODEL + h * DHEAD;

    // staging: thread = (t-pair sp, 8 elems at e0)  [R17-verified]
    {
        const int sp = tid & 31, mg = tid >> 5;
        const int e0 = mg * 8;
        const uint4 k0 = *reinterpret_cast<const uint4*>(
            &Kb[gbase + (size_t)(2 * sp) * D_MODEL + e0]);
        const uint4 k1 = *reinterpret_cast<const uint4*>(
            &Kb[gbase + (size_t)(2 * sp + 1) * D_MODEL + e0]);
        const uint4 v0 = *reinterpret_cast<const uint4*>(
            &Vb[gbase + (size_t)(2 * sp) * D_MODEL + e0]);
        const uint4 v1 = *reinterpret_cast<const uint4*>(
            &Vb[gbase + (size_t)(2 * sp + 1) * D_MODEL + e0]);
        const unsigned short* ke = reinterpret_cast<const unsigned short*>(&k0);
        const unsigned short* ko2 = reinterpret_cast<const unsigned short*>(&k1);
        const unsigned short* ve = reinterpret_cast<const unsigned short*>(&v0);
        const unsigned short* vo = reinterpret_cast<const unsigned short*>(&v1);
#pragma unroll
        for (int j = 0; j < 8; ++j) {
            Ktp[(e0 + j) * PQ + sp] =
                (unsigned int)ke[j] | ((unsigned int)ko2[j] << 16);
            Vtp[(e0 + j) * PQ + sp] =
                (unsigned int)ve[j] | ((unsigned int)vo[j] << 16);
        }
    }
    __syncthreads();

    const int wave = tid >> 6, lane = tid & 63;
    const int la = lane & 15, q = lane >> 4;
    const int wm = (wave >> 1) * 32, wn = (wave & 1) * 32;   // m rows, d cols

    f32x4 acc[2][2];
#pragma unroll
    for (int i = 0; i < 2; ++i)
#pragma unroll
        for (int j = 0; j < 2; ++j) acc[i][j] = (f32x4){0.f, 0.f, 0.f, 0.f};

#pragma unroll
    for (int ks = 0; ks < 2; ++ks) {
        const int ku = ks * 16 + q * 4;                      // uint offset (k=t)
        const bf16x8 a0  = __builtin_bit_cast(bf16x8,
            *reinterpret_cast<const uint4*>(&Vtp[(wm + la) * PQ + ku]));
        const bf16x8 a1  = __builtin_bit_cast(bf16x8,
            *reinterpret_cast<const uint4*>(&Vtp[(wm + 16 + la) * PQ + ku]));
        const bf16x8 bb0 = __builtin_bit_cast(bf16x8,
            *reinterpret_cast<const uint4*>(&Ktp[(wn + la) * PQ + ku]));
        const bf16x8 bb1 = __builtin_bit_cast(bf16x8,
            *reinterpret_cast<const uint4*>(&Ktp[(wn + 16 + la) * PQ + ku]));
        acc[0][0] = __builtin_amdgcn_mfma_f32_16x16x32_bf16(a0, bb0, acc[0][0], 0, 0, 0);
        acc[0][1] = __builtin_amdgcn_mfma_f32_16x16x32_bf16(a0, bb1, acc[0][1], 0, 0, 0);
        acc[1][0] = __builtin_amdgcn_mfma_f32_16x16x32_bf16(a1, bb0, acc[1][0], 0, 0, 0);
        acc[1][1] = __builtin_amdgcn_mfma_f32_16x16x32_bf16(a1, bb1, acc[1][1], 0, 0, 0);
    }

    unsigned short* Pb = Pb16 + (size_t)blockIdx.x * (DHEAD * DHEAD);
#pragma unroll
    for (int mi = 0; mi < 2; ++mi)
#pragma unroll
        for (int ni = 0; ni < 2; ++ni) {
            const int row = wm + mi * 16 + q * 4;   // m
            const int col = wn + ni * 16 + la;      // d
#pragma unroll
            for (int r = 0; r < 4; ++r)
                Pb[(row + r) * DHEAD + col] = f2bf(acc[mi][ni][r]);
        }

    if (tid < DHEAD) {
        float z = 0.f;
        for (int tt = 0; tt < 32; ++tt) {
            float lo, hi;
            unpack2(Ktp[tid * PQ + tt], lo, hi);
            z += lo;
            z += hi;
        }
        Zc[(size_t)blockIdx.x * DHEAD + tid] = z;
    }
}

// ---------------------------------------------------------------------------
// prefix — exclusive scan; NEW: reads bf16 P (scalar ushort loads, verified
// class), accumulates fp32, emits packed-bf16 Sb (R17-verified).
// ---------------------------------------------------------------------------
__global__ __launch_bounds__(256) void prefix_kernel(
    const unsigned short* __restrict__ Pb16, float* __restrict__ Zc,
    unsigned short* __restrict__ Sb)
{
    const int tid = threadIdx.x;
    if (blockIdx.x < NBH * 16) {
        const int bh = blockIdx.x >> 4;
        const int e = ((blockIdx.x & 15) << 8) + tid;
        const size_t base = (size_t)bh * NCHUNK * (DHEAD * DHEAD) + e;
        float v[NCHUNK];
#pragma unroll
        for (int c = 0; c < NCHUNK; ++c)
            v[c] = bf2f(Pb16[base + (size_t)c * (DHEAD * DHEAD)]);
        float s = 0.f;
#pragma unroll
        for (int c = 0; c < NCHUNK; ++c) {
            const float t = v[c];
            Sb[base + (size_t)c * (DHEAD * DHEAD)] = f2bf(s);
            s += t;
        }
    } else {
        const int j = ((int)(blockIdx.x - NBH * 16) << 8) + tid;
        if (j < NBH * DHEAD) {
            const int bh = j >> 6, d = j & 63;
            float v[NCHUNK];
#pragma unroll
            for (int c = 0; c < NCHUNK; ++c) v[c] = Zc[(bh * NCHUNK + c) * DHEAD + d];
            float s = 0.f;
#pragma unroll
            for (int c = 0; c < NCHUNK; ++c) {
                const float t = v[c];
                Zc[(bh * NCHUNK + c) * DHEAD + d] = s;
                s += t;
            }
        }
    }
}

// ---------------------------------------------------------------------------
// chunkout (R17-verified): packed LDS Q/K/V, Sb B-frags as uint4 from global.
// ---------------------------------------------------------------------------
__global__ __launch_bounds__(256) void chunkout_kernel(
    const unsigned short* __restrict__ Qb, const unsigned short* __restrict__ Kb,
    const unsigned short* __restrict__ Vb,
    const unsigned short* __restrict__ Sb, const float* __restrict__ Zx,
    unsigned short* __restrict__ Ob)
{
    __shared__ __align__(16) unsigned int Qp[CHUNK * PQ];   // packed [t][d/2]
    __shared__ __align__(16) unsigned int Kp[CHUNK * PQ];   // packed [s][d/2]
    __shared__ __align__(16) unsigned int Vtp[DHEAD * PQ];  // packed [m][s/2]
    __shared__ __align__(16) float At[CHUNK * LSTRF];       // fp32 [t][s]
    __shared__ float zsh[DHEAD];
    __shared__ float dnm[CHUNK];

    const int tid = threadIdx.x;
    const int c  = blockIdx.x % NCHUNK;
    const int bh = blockIdx.x / NCHUNK;
    const int b = bh / NHEADS, h = bh % NHEADS;
    const size_t gbase = ((size_t)(b * TSEQ + c * CHUNK)) * D_MODEL + h * DHEAD;
    const unsigned short* Sp = Sb + (size_t)blockIdx.x * (DHEAD * DHEAD);

    // stage Q,K: straight packed 16B copies (no conversion)
#pragma unroll
    for (int i = 0; i < 2; ++i) {
        const int idx = i * 256 + tid;           // 0..511
        const int t = idx >> 3, e4 = (idx & 7) * 4;   // uint offset in row
        const uint4 qv = *reinterpret_cast<const uint4*>(
            &Qb[gbase + (size_t)t * D_MODEL + e4 * 2]);
        const uint4 kv = *reinterpret_cast<const uint4*>(
            &Kb[gbase + (size_t)t * D_MODEL + e4 * 2]);
        *reinterpret_cast<uint4*>(&Qp[t * PQ + e4]) = qv;
        *reinterpret_cast<uint4*>(&Kp[t * PQ + e4]) = kv;
    }
    // stage V transposed, packed along s: thread = (s-pair, 8 m's)
    {
        const int sp = tid & 31, mg = tid >> 5;
        const int m0 = mg * 8;
        const uint4 v0 = *reinterpret_cast<const uint4*>(
            &Vb[gbase + (size_t)(2 * sp) * D_MODEL + m0]);
        const uint4 v1 = *reinterpret_cast<const uint4*>(
            &Vb[gbase + (size_t)(2 * sp + 1) * D_MODEL + m0]);
        const unsigned short* ev = reinterpret_cast<const unsigned short*>(&v0);
        const unsigned short* ov = reinterpret_cast<const unsigned short*>(&v1);
#pragma unroll
        for (int j = 0; j < 8; ++j)
            Vtp[(m0 + j) * PQ + sp] =
                (unsigned int)ev[j] | ((unsigned int)ov[j] << 16);
    }
    if (tid < DHEAD)
        zsh[tid] = Zx[((size_t)bh * NCHUNK + c) * DHEAD + tid];
    __syncthreads();

    const int wave = tid >> 6, lane = tid & 63;
    const int la = lane & 15, q = lane >> 4;
    const int wt = (wave >> 1) * 32, wn = (wave & 1) * 32;

    // phase 1: A = Q K^T
    f32x4 acc[2][2];
#pragma unroll
    for (int i = 0; i < 2; ++i)
#pragma unroll
        for (int j = 0; j < 2; ++j) acc[i][j] = (f32x4){0.f, 0.f, 0.f, 0.f};
#pragma unroll
    for (int ks = 0; ks < 2; ++ks) {
        const int ku = ks * 16 + q * 4;                      // uint offset (k=d)
        const bf16x8 a0  = __builtin_bit_cast(bf16x8,
            *reinterpret_cast<const uint4*>(&Qp[(wt + la) * PQ + ku]));
        const bf16x8 a1  = __builtin_bit_cast(bf16x8,
            *reinterpret_cast<const uint4*>(&Qp[(wt + 16 + la) * PQ + ku]));
        const bf16x8 bb0 = __builtin_bit_cast(bf16x8,
            *reinterpret_cast<const uint4*>(&Kp[(wn + la) * PQ + ku]));
        const bf16x8 bb1 = __builtin_bit_cast(bf16x8,
            *reinterpret_cast<const uint4*>(&Kp[(wn + 16 + la) * PQ + ku]));
        acc[0][0] = __builtin_amdgcn_mfma_f32_16x16x32_bf16(a0, bb0, acc[0][0], 0, 0, 0);
        acc[0][1] = __builtin_amdgcn_mfma_f32_16x16x32_bf16(a0, bb1, acc[0][1], 0, 0, 0);
        acc[1][0] = __builtin_amdgcn_mfma_f32_16x16x32_bf16(a1, bb0, acc[1][0], 0, 0, 0);
        acc[1][1] = __builtin_amdgcn_mfma_f32_16x16x32_bf16(a1, bb1, acc[1][1], 0, 0, 0);
    }
#pragma unroll
    for (int mi = 0; mi < 2; ++mi)
#pragma unroll
        for (int ni = 0; ni < 2; ++ni) {
            const int t0 = wt + mi * 16 + q * 4;
            const int s  = wn + ni * 16 + la;
#pragma unroll
            for (int r = 0; r < 4; ++r)
                At[(t0 + r) * LSTRF + s] = (s <= t0 + r) ? acc[mi][ni][r] : 0.f;
        }
    __syncthreads();

    // phase 2: denom[t] = rowsum(A) + Q . Z_prev + eps  (Q via unpack2)
    if (tid < CHUNK) {
        float dv = 0.f;
        for (int s = 0; s < CHUNK; ++s) dv += At[tid * LSTRF + s];
        for (int dd = 0; dd < 32; ++dd) {
            float lo, hi;
            unpack2(Qp[tid * PQ + dd], lo, hi);
            dv = fmaf(lo, zsh[2 * dd], dv);
            dv = fmaf(hi, zsh[2 * dd + 1], dv);
        }
        dnm[tid] = dv + EPSV;
    }
    __syncthreads();

    // phase 3: O = Q @ S_prev + A @ V
    f32x4 o[2][2];
#pragma unroll
    for (int i = 0; i < 2; ++i)
#pragma unroll
        for (int j = 0; j < 2; ++j) o[i][j] = (f32x4){0.f, 0.f, 0.f, 0.f};
#pragma unroll
    for (int ks = 0; ks < 2; ++ks) {
        const int ku = ks * 16 + q * 4;                      // uint offset (k=d)
        const int ko = ks * 32 + q * 8;                      // elem offset
        const bf16x8 a0  = __builtin_bit_cast(bf16x8,
            *reinterpret_cast<const uint4*>(&Qp[(wt + la) * PQ + ku]));
        const bf16x8 a1  = __builtin_bit_cast(bf16x8,
            *reinterpret_cast<const uint4*>(&Qp[(wt + 16 + la) * PQ + ku]));
        const bf16x8 bb0 = __builtin_bit_cast(bf16x8,
            *reinterpret_cast<const uint4*>(&Sp[(wn + la) * DHEAD + ko]));      // global, packed
        const bf16x8 bb1 = __builtin_bit_cast(bf16x8,
            *reinterpret_cast<const uint4*>(&Sp[(wn + 16 + la) * DHEAD + ko])); // global, packed
        o[0][0] = __builtin_amdgcn_mfma_f32_16x16x32_bf16(a0, bb0, o[0][0], 0, 0, 0);
        o[0][1] = __builtin_amdgcn_mfma_f32_16x16x32_bf16(a0, bb1, o[0][1], 0, 0, 0);
        o[1][0] = __builtin_amdgcn_mfma_f32_16x16x32_bf16(a1, bb0, o[1][0], 0, 0, 0);
        o[1][1] = __builtin_amdgcn_mfma_f32_16x16x32_bf16(a1, bb1, o[1][1], 0, 0, 0);
    }
#pragma unroll
    for (int ks = 0; ks < 2; ++ks) {
        const int ku = ks * 16 + q * 4;                      // uint offset (k=s)
        const int ko = ks * 32 + q * 8;
        const bf16x8 a0  = frag8(&At[(wt + la) * LSTRF + ko]);
        const bf16x8 a1  = frag8(&At[(wt + 16 + la) * LSTRF + ko]);
        const bf16x8 bb0 = __builtin_bit_cast(bf16x8,
            *reinterpret_cast<const uint4*>(&Vtp[(wn + la) * PQ + ku]));
        const bf16x8 bb1 = __builtin_bit_cast(bf16x8,
            *reinterpret_cast<const uint4*>(&Vtp[(wn + 16 + la) * PQ + ku]));
        o[0][0] = __builtin_amdgcn_mfma_f32_16x16x32_bf16(a0, bb0, o[0][0], 0, 0, 0);
        o[0][1] = __builtin_amdgcn_mfma_f32_16x16x32_bf16(a0, bb1, o[0][1], 0, 0, 0);
        o[1][0] = __builtin_amdgcn_mfma_f32_16x16x32_bf16(a1, bb0, o[1][0], 0, 0, 0);
        o[1][1] = __builtin_amdgcn_mfma_f32_16x16x32_bf16(a1, bb1, o[1][1], 0, 0, 0);
    }

    // epilogue: divide + bf16 scalar stores (verified class)
#pragma unroll
    for (int mi = 0; mi < 2; ++mi)
#pragma unroll
        for (int ni = 0; ni < 2; ++ni) {
            const int t0 = wt + mi * 16 + q * 4;
            const int m  = wn + ni * 16 + la;
#pragma unroll
            for (int r = 0; r < 4; ++r) {
                const float v = o[mi][ni][r] / dnm[t0 + r];
                Ob[gbase + (size_t)(t0 + r) * D_MODEL + m] = f2bf(v);
            }
        }
}

extern "C" void kernel_launch(void* const* d_in, const int* in_sizes, int n_in,
                              void* d_out, int out_size, void* d_ws, size_t ws_size,
                              hipStream_t stream)
{
    const float* x  = (const float*)d_in[0];
    const float* Wq = (const float*)d_in[1];
    const float* bq = (const float*)d_in[2];
    const float* Wk = (const float*)d_in[3];
    const float* bk = (const float*)d_in[4];
    const float* Wv = (const float*)d_in[5];
    const float* bv = (const float*)d_in[6];
    const float* Wo = (const float*)d_in[7];
    const float* bo = (const float*)d_in[8];
    float* out = (float*)d_out;

    const size_t NE = (size_t)NTOK * D_MODEL;               // 2M elems
    const size_t PE = (size_t)NBH * NCHUNK * DHEAD * DHEAD; // 2M elems
    unsigned short* xb   = (unsigned short*)d_ws;           // 2M bf16
    unsigned short* Wt   = xb + NE;                         // 768*256
    unsigned short* Wot  = Wt + 768 * 256;                  // 256*256
    unsigned short* Qb   = Wot + 256 * 256;                 // 2M
    unsigned short* Kb   = Qb + NE;                         // 2M
    unsigned short* Vb   = Kb + NE;                         // 2M
    unsigned short* Ob   = Vb + NE;                         // 2M
    unsigned short* Sb   = Ob + NE;                         // 2M bf16
    unsigned short* Pb16 = Sb + PE;                         // 2M bf16
    float* Z = (float*)(Pb16 + PE);                         // 16*32*64 f32

    convert_kernel<<<NTOK * D_MODEL / 8 / 256 + 64, 256, 0, stream>>>(
        x, Wq, Wk, Wv, Wo, xb, Wt, Wot);
    mfma_gemm_kernel<0><<<(NTOK / 64) * 12, 256, 0, stream>>>(
        xb, Wt, bq, bk, bv, Qb, Kb, Vb);
    chunksum_kernel<<<NBH * NCHUNK, 256, 0, stream>>>(Kb, Vb, Pb16, Z);
    prefix_kernel<<<NBH * 16 + 4, 256, 0, stream>>>(Pb16, Z, Sb);
    chunkout_kernel<<<NBH * NCHUNK, 256, 0, stream>>>(Qb, Kb, Vb, Sb, Z, Ob);
    mfma_gemm_kernel<1><<<(NTOK / 64) * 4, 256, 0, stream>>>(
        Ob, Wot, bo, nullptr, nullptr, out, nullptr, nullptr);
}